// Round 4
// baseline (1216.149 us; speedup 1.0000x reference)
//
#include <hip/hip_runtime.h>
#include <cstdint>

#define NN   50000
#define SS   2048
#define KSUB 64
#define HH   128
#define EE   (SS * 256)
#define SKK  (SS * KSUB)    // 131072
#define LLAY 5
#define NBLK 196            // ceil(NN/256)

typedef __attribute__((ext_vector_type(8))) short bhalf8;
typedef __attribute__((ext_vector_type(4))) float f32x4;

__device__ __forceinline__ ushort f2b(float f) {
  uint u = __builtin_bit_cast(uint, f);
  uint r = (u + 0x7FFFu + ((u >> 16) & 1u)) >> 16;
  return (ushort)r;
}
__device__ __forceinline__ float b2f(ushort u) {
  uint v = ((uint)u) << 16;
  return __builtin_bit_cast(float, v);
}
// split fp32 -> (hi, lo) bf16 pair; hi + lo ~= f with ~2^-18 residual
__device__ __forceinline__ void fsplit(float f, ushort& hi, ushort& lo) {
  hi = f2b(f);
  lo = f2b(f - b2f(hi));
}
// byte offset into a [64][128]-short LDS tile, T2 XOR swizzle (row stride 256B)
__device__ __forceinline__ int zoff(int row, int col) {
  return row * 256 + (((col * 2) & 255) ^ ((row & 7) << 4));
}

// ---------------------------------------------------------------------------
// Fold node_proj through init_proj; emit split bf16 B^T layout [n][c]
// ---------------------------------------------------------------------------
__global__ void fold_M_k(const float* __restrict__ Wn, const float* __restrict__ Wi,
                         ushort* __restrict__ Mth, ushort* __restrict__ Mtl) {
  int c = blockIdx.x, n = threadIdx.x;
  float s = 0.f;
  for (int k = 0; k < HH; ++k) s = fmaf(Wn[c * HH + k], Wi[k * HH + n], s);
  ushort hi, lo; fsplit(s, hi, lo);
  Mth[n * HH + c] = hi; Mtl[n * HH + c] = lo;
}

__global__ void fold_vec_k(const float* __restrict__ Wi, const float* __restrict__ wl,
                           const float* __restrict__ bnb, const float* __restrict__ blb,
                           const float* __restrict__ bi, const float* __restrict__ remb,
                           float* __restrict__ vl, float* __restrict__ c0,
                           float* __restrict__ rev) {
  int n = threadIdx.x;
  float svl = 0.f, sc0 = bi[n], r0 = 0.f, r1 = 0.f;
  for (int k = 0; k < HH; ++k) {
    svl = fmaf(wl[k], Wi[(HH + k) * HH + n], svl);
    sc0 = fmaf(bnb[k], Wi[k * HH + n], sc0);
    sc0 = fmaf(blb[k], Wi[(HH + k) * HH + n], sc0);
    r0  = fmaf(remb[k],      Wi[(2 * HH + k) * HH + n], r0);
    r1  = fmaf(remb[HH + k], Wi[(2 * HH + k) * HH + n], r1);
  }
  vl[n] = svl; c0[n] = sc0; rev[n] = r0; rev[HH + n] = r1;
}

// ---------------------------------------------------------------------------
// Transpose+convert all layer weights to split bf16 B^T layout (one launch).
// ---------------------------------------------------------------------------
__global__ void wconv_k(const float* __restrict__ w1, const float* __restrict__ w2,
                        const float* __restrict__ mp2w,
                        ushort* __restrict__ w1th, ushort* __restrict__ w1tl,
                        ushort* __restrict__ w2th, ushort* __restrict__ w2tl,
                        ushort* __restrict__ mp2th, ushort* __restrict__ mp2tl) {
  int b = blockIdx.x, n = threadIdx.x;
  ushort hi, lo;
  if (b < 640) {
    int l = b >> 7, k = b & 127;
    fsplit(w1[((size_t)l * HH + k) * HH + n], hi, lo);
    w1th[((size_t)l * HH + n) * HH + k] = hi;
    w1tl[((size_t)l * HH + n) * HH + k] = lo;
  } else if (b < 1280) {
    int bb = b - 640; int l = bb >> 7, k = bb & 127;
    fsplit(w2[((size_t)l * HH + k) * HH + n], hi, lo);
    w2th[((size_t)l * HH + n) * HH + k] = hi;
    w2tl[((size_t)l * HH + n) * HH + k] = lo;
  } else {
    int bb = b - 1280; int l = bb >> 8, k = bb & 255;
    fsplit(mp2w[((size_t)l * 256 + k) * HH + n], hi, lo);
    mp2th[((size_t)l * HH + n) * 256 + k] = hi;
    mp2tl[((size_t)l * HH + n) * 256 + k] = lo;
  }
}

// ---------------------------------------------------------------------------
// Node-CSR construction: count -> exclusive scan -> fill
// ---------------------------------------------------------------------------
__global__ void count_k(const int* __restrict__ idc, int* __restrict__ cnt) {
  int i = blockIdx.x * 256 + threadIdx.x;
  if (i < SKK) atomicAdd(&cnt[idc[i]], 1);
}

__global__ void scan1_k(const int* __restrict__ cnt, int* __restrict__ excl,
                        int* __restrict__ bsum) {
  __shared__ int sh[256];
  const int tid = threadIdx.x;
  const int i = blockIdx.x * 256 + tid;
  int v = (i < NN) ? cnt[i] : 0;
  sh[tid] = v;
  __syncthreads();
#pragma unroll
  for (int off = 1; off < 256; off <<= 1) {
    int t = (tid >= off) ? sh[tid - off] : 0;
    __syncthreads();
    sh[tid] += t;
    __syncthreads();
  }
  excl[i] = sh[tid] - v;
  if (tid == 255) bsum[blockIdx.x] = sh[tid];
}

__global__ void scan2_k(int* __restrict__ bsum, int* __restrict__ boff) {
  __shared__ int sh[256];
  const int tid = threadIdx.x;
  int v = (tid < NBLK) ? bsum[tid] : 0;
  sh[tid] = v;
  __syncthreads();
#pragma unroll
  for (int off = 1; off < 256; off <<= 1) {
    int t = (tid >= off) ? sh[tid - off] : 0;
    __syncthreads();
    sh[tid] += t;
    __syncthreads();
  }
  boff[tid] = sh[tid] - v;
}

__global__ void scan3_k(const int* __restrict__ excl, const int* __restrict__ boff,
                        int* __restrict__ node_ptr) {
  int i = blockIdx.x * 256 + threadIdx.x;
  if (i < NN) node_ptr[i] = excl[i] + boff[blockIdx.x];
  if (i == 0) node_ptr[NN] = SKK;
}

__global__ void fill_rows_k(const int* __restrict__ idc, const int* __restrict__ node_ptr,
                            int* __restrict__ cur, int* __restrict__ rowlist) {
  int i = blockIdx.x * 256 + threadIdx.x;
  if (i < SKK) {
    int id = idc[i];
    int pos = atomicAdd(&cur[id], 1);
    rowlist[node_ptr[id] + pos] = i;
  }
}

// ---------------------------------------------------------------------------
// Cross-subgraph scatter-mean as a GATHER (split in, fp32 acc, split out)
// ---------------------------------------------------------------------------
__launch_bounds__(256)
__global__ void scatter_mean_k(const ushort* __restrict__ zh, const ushort* __restrict__ zl,
                               const int* __restrict__ node_ptr,
                               const int* __restrict__ rowlist,
                               ushort* __restrict__ xah, ushort* __restrict__ xal) {
  const int tid = threadIdx.x;
  const int n = blockIdx.x * 2 + (tid >> 7);
  if (n >= NN) return;
  const int c = tid & 127;
  const int p0 = node_ptr[n], p1 = node_ptr[n + 1];
  float s = 0.f;
  for (int p = p0; p < p1; ++p) {
    const size_t off = (size_t)rowlist[p] * HH + c;
    s += b2f(zh[off]) + b2f(zl[off]);
  }
  const float inv = 1.0f / (float)max(p1 - p0, 1);
  ushort hi, lo; fsplit(s * inv, hi, lo);
  xah[(size_t)n * HH + c] = hi;
  xal[(size_t)n * HH + c] = lo;
}

// ---------------------------------------------------------------------------
// Per-subgraph counting sort of edges by dst -> CSR
// ---------------------------------------------------------------------------
__launch_bounds__(256)
__global__ void presort_k(const int* __restrict__ e_src, const int* __restrict__ e_dst,
                          const int* __restrict__ edge_ptr, int* __restrict__ row_ptr,
                          int* __restrict__ ssrc) {
  __shared__ int cnt[KSUB];
  __shared__ int base[KSUB];
  __shared__ int cur[KSUB];
  const int s = blockIdx.x, tid = threadIdx.x;
  const int p0 = edge_ptr[s], p1 = edge_ptr[s + 1];
  if (tid < KSUB) cnt[tid] = 0;
  __syncthreads();
  for (int e = p0 + tid; e < p1; e += 256) atomicAdd(&cnt[e_dst[e]], 1);
  __syncthreads();
  if (tid == 0) {
    int a = 0;
    for (int d = 0; d < KSUB; ++d) { base[d] = a; a += cnt[d]; }
  }
  __syncthreads();
  if (tid < KSUB) { row_ptr[s * KSUB + tid] = p0 + base[tid]; cur[tid] = base[tid]; }
  if (s == 0 && tid == 0) row_ptr[SS * KSUB] = edge_ptr[SS];
  __syncthreads();
  for (int e = p0 + tid; e < p1; e += 256) {
    int d = e_dst[e];
    int pos = atomicAdd(&cur[d], 1);
    ssrc[p0 + pos] = e_src[e];
  }
}

// ---------------------------------------------------------------------------
// MEGA kernel: per subgraph (64 rows):
//   phase A: h_new = bn(uf) + h_old (residual) [skip BN if FIRST];
//            BN coef computed INLINE from stats (replaces bn_finalize_k);
//            write h_new to global AND keep fp32 tile in LDS
//   phase B: GIN aggregation z_agg = (1+eps)h_new + sum_src h_new  (regs)
//   phase C: split z_agg -> swizzled bf16 LDS tile Z (aliases h tile)
//   MLP1:    t = relu(Z @ W1 + b1) -> swizzled LDS tile T (aliases Z)
//   MLP2:    z = T @ W2 + b2       -> global zh/zl (split)
// ---------------------------------------------------------------------------
template <bool FIRST>
__launch_bounds__(256, 4)
__global__ void gin_mega_k(float* __restrict__ h, const float* __restrict__ uf,
                           const float* __restrict__ stats,
                           const float* __restrict__ gamma, const float* __restrict__ beta,
                           const int* __restrict__ row_ptr, const int* __restrict__ ssrc,
                           const float* __restrict__ gin_eps, const int layer,
                           const ushort* __restrict__ B1h, const ushort* __restrict__ B1l,
                           const ushort* __restrict__ B2h, const ushort* __restrict__ B2l,
                           const float* __restrict__ bias1, const float* __restrict__ bias2,
                           ushort* __restrict__ zh, ushort* __restrict__ zl) {
  constexpr int LDH = 132;
  __shared__ __align__(16) char smem[KSUB * LDH * 4];   // 33792 B, phase-aliased
  float*  hl = (float*)smem;                 // [64][132] fp32 (phases A,B)
  ushort* Zh = (ushort*)smem;                // [64][128] swizzled (phases C..MLP2)
  ushort* Zl = (ushort*)(smem + KSUB * HH * 2);
  const int s = blockIdx.x, tid = threadIdx.x;
  const size_t base = (size_t)s * KSUB * HH;

  // ---- phase A (BN coef inline; c constant across 'it' since 1024 % 128 == 0) ----
  float csc[4], csh[4];
  const int cb = (tid * 4) & 127;
  if constexpr (!FIRST) {
    const float invM = 1.0f / (float)SKK;
#pragma unroll
    for (int e = 0; e < 4; ++e) {
      const float mu = stats[cb + e] * invM;
      const float var = fmaf(-mu, mu, stats[HH + cb + e] * invM);
      const float sc = rsqrtf(var + 1e-5f) * gamma[cb + e];
      csc[e] = sc; csh[e] = fmaf(-mu, sc, beta[cb + e]);
    }
  }
#pragma unroll
  for (int it = 0; it < 8; ++it) {
    const int idx = it * 1024 + tid * 4;
    const int m = idx >> 7, c = idx & 127;
    float4 hv = *(const float4*)&h[base + idx];
    if constexpr (!FIRST) {
      float4 u4 = *(const float4*)&uf[base + idx];
      hv.x += fmaf(u4.x, csc[0], csh[0]);
      hv.y += fmaf(u4.y, csc[1], csh[1]);
      hv.z += fmaf(u4.z, csc[2], csh[2]);
      hv.w += fmaf(u4.w, csc[3], csh[3]);
      *(float4*)&h[base + idx] = hv;
    }
    *(float4*)&hl[m * LDH + c] = hv;
  }
  __syncthreads();

  // ---- phase B: aggregation ----
  const float ep1 = 1.0f + gin_eps[layer];
  const int d = tid >> 2, cg = (tid & 3) * 32;
  const int g = s * KSUB + d;
  const int e0 = row_ptr[g], e1 = row_ptr[g + 1];
  float a[32];
  {
    const float* hp0 = &hl[d * LDH + cg];
#pragma unroll
    for (int j = 0; j < 8; ++j) {
      float4 v = *(const float4*)(hp0 + 4 * j);
      a[4 * j + 0] = ep1 * v.x; a[4 * j + 1] = ep1 * v.y;
      a[4 * j + 2] = ep1 * v.z; a[4 * j + 3] = ep1 * v.w;
    }
    for (int e = e0; e < e1; ++e) {
      const float* hp = &hl[ssrc[e] * LDH + cg];
#pragma unroll
      for (int j = 0; j < 8; ++j) {
        float4 v = *(const float4*)(hp + 4 * j);
        a[4 * j + 0] += v.x; a[4 * j + 1] += v.y;
        a[4 * j + 2] += v.z; a[4 * j + 3] += v.w;
      }
    }
  }
  __syncthreads();          // all hl reads done (Z aliases hl)

  // ---- phase C: split z_agg into swizzled LDS tile ----
#pragma unroll
  for (int q = 0; q < 4; ++q) {
    ushort th[8], tl[8];
#pragma unroll
    for (int e = 0; e < 8; ++e) fsplit(a[q * 8 + e], th[e], tl[e]);
    const int o = zoff(d, cg + q * 8);
    *(uint4*)((char*)Zh + o) = *(uint4*)th;
    *(uint4*)((char*)Zl + o) = *(uint4*)tl;
  }
  __syncthreads();

  // ---- MLP GEMMs ----
  const int lane = tid & 63, wv = tid >> 6;
  const int fr = lane & 15, quad = lane >> 4;
  const int nj0 = wv * 32 + fr, nj1 = nj0 + 16;

  f32x4 acc[4][2];
#pragma unroll
  for (int i = 0; i < 4; ++i) { acc[i][0] = (f32x4){0,0,0,0}; acc[i][1] = (f32x4){0,0,0,0}; }

  // MLP1: t = relu(Z @ W1 + b1)
#pragma unroll
  for (int ch = 0; ch < 4; ++ch) {
    bhalf8 afh[4], afl[4], bfh[2], bfl[2];
#pragma unroll
    for (int i = 0; i < 4; ++i) {
      const int o = zoff(i * 16 + fr, ch * 32 + quad * 8);
      afh[i] = *(const bhalf8*)((const char*)Zh + o);
      afl[i] = *(const bhalf8*)((const char*)Zl + o);
    }
#pragma unroll
    for (int j = 0; j < 2; ++j) {
      const size_t off = (size_t)(wv * 32 + j * 16 + fr) * HH + ch * 32 + quad * 8;
      bfh[j] = *(const bhalf8*)(B1h + off);
      bfl[j] = *(const bhalf8*)(B1l + off);
    }
#pragma unroll
    for (int i = 0; i < 4; ++i)
#pragma unroll
      for (int j = 0; j < 2; ++j) {
        acc[i][j] = __builtin_amdgcn_mfma_f32_16x16x32_bf16(afh[i], bfh[j], acc[i][j], 0, 0, 0);
        acc[i][j] = __builtin_amdgcn_mfma_f32_16x16x32_bf16(afl[i], bfh[j], acc[i][j], 0, 0, 0);
        acc[i][j] = __builtin_amdgcn_mfma_f32_16x16x32_bf16(afh[i], bfl[j], acc[i][j], 0, 0, 0);
      }
  }
  __syncthreads();          // all Z reads done (T aliases Z)

  // epilogue 1: T = relu(acc + b1), split, into swizzled LDS
  {
    const float b10 = bias1[nj0], b11 = bias1[nj1];
#pragma unroll
    for (int i = 0; i < 4; ++i)
#pragma unroll
      for (int r = 0; r < 4; ++r) {
        const int row = i * 16 + quad * 4 + r;
        const float o0 = fmaxf(acc[i][0][r] + b10, 0.f);
        const float o1 = fmaxf(acc[i][1][r] + b11, 0.f);
        ushort h0, l0, h1, l1; fsplit(o0, h0, l0); fsplit(o1, h1, l1);
        *(ushort*)((char*)Zh + zoff(row, nj0)) = h0;
        *(ushort*)((char*)Zl + zoff(row, nj0)) = l0;
        *(ushort*)((char*)Zh + zoff(row, nj1)) = h1;
        *(ushort*)((char*)Zl + zoff(row, nj1)) = l1;
      }
  }
  __syncthreads();

  // MLP2: z = T @ W2 + b2
#pragma unroll
  for (int i = 0; i < 4; ++i) { acc[i][0] = (f32x4){0,0,0,0}; acc[i][1] = (f32x4){0,0,0,0}; }
#pragma unroll
  for (int ch = 0; ch < 4; ++ch) {
    bhalf8 afh[4], afl[4], bfh[2], bfl[2];
#pragma unroll
    for (int i = 0; i < 4; ++i) {
      const int o = zoff(i * 16 + fr, ch * 32 + quad * 8);
      afh[i] = *(const bhalf8*)((const char*)Zh + o);
      afl[i] = *(const bhalf8*)((const char*)Zl + o);
    }
#pragma unroll
    for (int j = 0; j < 2; ++j) {
      const size_t off = (size_t)(wv * 32 + j * 16 + fr) * HH + ch * 32 + quad * 8;
      bfh[j] = *(const bhalf8*)(B2h + off);
      bfl[j] = *(const bhalf8*)(B2l + off);
    }
#pragma unroll
    for (int i = 0; i < 4; ++i)
#pragma unroll
      for (int j = 0; j < 2; ++j) {
        acc[i][j] = __builtin_amdgcn_mfma_f32_16x16x32_bf16(afh[i], bfh[j], acc[i][j], 0, 0, 0);
        acc[i][j] = __builtin_amdgcn_mfma_f32_16x16x32_bf16(afl[i], bfh[j], acc[i][j], 0, 0, 0);
        acc[i][j] = __builtin_amdgcn_mfma_f32_16x16x32_bf16(afh[i], bfl[j], acc[i][j], 0, 0, 0);
      }
  }

  // epilogue 2: z -> global (split)
  {
    const float b20 = bias2[nj0], b21 = bias2[nj1];
#pragma unroll
    for (int i = 0; i < 4; ++i)
#pragma unroll
      for (int r = 0; r < 4; ++r) {
        const int row = i * 16 + quad * 4 + r;
        const size_t gb = base + (size_t)row * HH;
        const float o0 = acc[i][0][r] + b20;
        const float o1 = acc[i][1][r] + b21;
        ushort h0, l0, h1, l1; fsplit(o0, h0, l0); fsplit(o1, h1, l1);
        zh[gb + nj0] = h0; zl[gb + nj0] = l0;
        zh[gb + nj1] = h1; zl[gb + nj1] = l1;
      }
  }
}

// ---------------------------------------------------------------------------
// MP-2 GEMM, gin_mega-style: 64-row blocks, grid SKK/64 = 2048, 4 blocks/CU.
// u = relu([z | xa[idc]] @ W + b), W in [n][256] split layout.
// One 32KB swizzled LDS tile reused for both K-halves:
//   stage z rows (contiguous) -> GEMM vs W[:,0:128]
//   stage xa[idc] rows (gather) -> GEMM vs W[:,128:256]
// Epilogue: relu, uf write (fp32), BN stats via LDS + global atomics.
// ---------------------------------------------------------------------------
__launch_bounds__(256, 4)
__global__ void mp2_k(const ushort* __restrict__ zh, const ushort* __restrict__ zl,
                      const ushort* __restrict__ xah, const ushort* __restrict__ xal,
                      const ushort* __restrict__ Bh, const ushort* __restrict__ Bl,
                      const float* __restrict__ bias, float* __restrict__ uf,
                      const int* __restrict__ idc, float* __restrict__ stats) {
  __shared__ __align__(16) char smem[KSUB * HH * 2 * 2];   // 32 KB: Th,Tl
  __shared__ float sred[2 * HH];
  ushort* Th = (ushort*)smem;
  ushort* Tl = (ushort*)(smem + KSUB * HH * 2);
  const int tid = threadIdx.x;
  const int row0 = blockIdx.x * 64;
  const int sr = tid >> 2, qq = tid & 3;      // staging: row, 32-short chunk
  const int lane = tid & 63, wv = tid >> 6;
  const int fr = lane & 15, quad = lane >> 4;
  const int nj0 = wv * 32 + fr, nj1 = nj0 + 16;

  f32x4 acc[4][2];
#pragma unroll
  for (int i = 0; i < 4; ++i) { acc[i][0] = (f32x4){0,0,0,0}; acc[i][1] = (f32x4){0,0,0,0}; }

#pragma unroll
  for (int half = 0; half < 2; ++half) {
    // ---- stage A half-tile (swizzled) ----
    {
      size_t src;
      const ushort *ah, *al;
      if (half == 0) {
        src = (size_t)(row0 + sr) * HH + qq * 32;
        ah = zh; al = zl;
      } else {
        src = (size_t)idc[row0 + sr] * HH + qq * 32;
        ah = xah; al = xal;
      }
#pragma unroll
      for (int q = 0; q < 4; ++q) {
        const int o = zoff(sr, qq * 32 + q * 8);
        *(uint4*)((char*)Th + o) = *(const uint4*)(ah + src + q * 8);
        *(uint4*)((char*)Tl + o) = *(const uint4*)(al + src + q * 8);
      }
    }
    __syncthreads();
    // ---- GEMM half: acc += T @ W[:, half*128 : half*128+128] ----
#pragma unroll
    for (int ch = 0; ch < 4; ++ch) {
      bhalf8 afh[4], afl[4], bfh[2], bfl[2];
#pragma unroll
      for (int i = 0; i < 4; ++i) {
        const int o = zoff(i * 16 + fr, ch * 32 + quad * 8);
        afh[i] = *(const bhalf8*)((const char*)Th + o);
        afl[i] = *(const bhalf8*)((const char*)Tl + o);
      }
#pragma unroll
      for (int j = 0; j < 2; ++j) {
        const size_t off = (size_t)(wv * 32 + j * 16 + fr) * 256 + half * 128 + ch * 32 + quad * 8;
        bfh[j] = *(const bhalf8*)(Bh + off);
        bfl[j] = *(const bhalf8*)(Bl + off);
      }
#pragma unroll
      for (int i = 0; i < 4; ++i)
#pragma unroll
        for (int j = 0; j < 2; ++j) {
          acc[i][j] = __builtin_amdgcn_mfma_f32_16x16x32_bf16(afh[i], bfh[j], acc[i][j], 0, 0, 0);
          acc[i][j] = __builtin_amdgcn_mfma_f32_16x16x32_bf16(afl[i], bfh[j], acc[i][j], 0, 0, 0);
          acc[i][j] = __builtin_amdgcn_mfma_f32_16x16x32_bf16(afh[i], bfl[j], acc[i][j], 0, 0, 0);
        }
    }
    if (half == 0) __syncthreads();   // tile reused for the gather half
  }

  // ---- epilogue: relu + bias, uf write, BN stats ----
  const float b0 = bias[nj0], b1 = bias[nj1];
  float psum0 = 0.f, psq0 = 0.f, psum1 = 0.f, psq1 = 0.f;
#pragma unroll
  for (int i = 0; i < 4; ++i)
#pragma unroll
    for (int r = 0; r < 4; ++r) {
      const int row = i * 16 + quad * 4 + r;
      const size_t gb = (size_t)(row0 + row) * HH;
      const float o0 = fmaxf(acc[i][0][r] + b0, 0.f);
      const float o1 = fmaxf(acc[i][1][r] + b1, 0.f);
      uf[gb + nj0] = o0;
      uf[gb + nj1] = o1;
      psum0 += o0; psq0 += o0 * o0;
      psum1 += o1; psq1 += o1 * o1;
    }
  sred[tid] = 0.f;
  __syncthreads();
  atomicAdd(&sred[nj0], psum0);
  atomicAdd(&sred[HH + nj0], psq0);
  atomicAdd(&sred[nj1], psum1);
  atomicAdd(&sred[HH + nj1], psq1);
  __syncthreads();
  unsafeAtomicAdd(&stats[tid], sred[tid]);
}

// ---------------------------------------------------------------------------
// Split-bf16 MFMA GEMM (round-0 verified LDS-staged version) — MODE 0 only.
// ---------------------------------------------------------------------------
__launch_bounds__(256, 2)
__global__ void mgemm0_k(const float* __restrict__ Afp,
                         const ushort* __restrict__ Bh, const ushort* __restrict__ Bl,
                         float* __restrict__ Cf,
                         const int* __restrict__ idc, const float* __restrict__ log_probs,
                         const int* __restrict__ root_local, const float* __restrict__ vl,
                         const float* __restrict__ c0v, const float* __restrict__ rev) {
  constexpr int LDP = 40;
  __shared__ __align__(16) ushort Ash[128 * LDP];
  __shared__ __align__(16) ushort Asl[128 * LDP];
  __shared__ __align__(16) ushort Bsh[128 * LDP];
  __shared__ __align__(16) ushort Bsl[128 * LDP];
  const int tid = threadIdx.x;
  const int row0 = blockIdx.x * 128;
  const int lane = tid & 63, wv = tid >> 6;
  const int wm = (wv >> 1) * 64, wn = (wv & 1) * 64;
  const int fr = lane & 15, quad = lane >> 4;
  const int sr = tid >> 1;
  const int sc = (tid & 1) * 16;

  f32x4 acc[4][4];
#pragma unroll
  for (int i = 0; i < 4; ++i)
#pragma unroll
    for (int j = 0; j < 4; ++j) acc[i][j] = (f32x4){0.f, 0.f, 0.f, 0.f};

  for (int ch = 0; ch < 4; ++ch) {
    {
      const float* src = Afp + (size_t)idc[row0 + sr] * HH + ch * 32 + sc;
      float fv[16];
      *(float4*)&fv[0]  = *(const float4*)(src);
      *(float4*)&fv[4]  = *(const float4*)(src + 4);
      *(float4*)&fv[8]  = *(const float4*)(src + 8);
      *(float4*)&fv[12] = *(const float4*)(src + 12);
      ushort hi[16], lo[16];
#pragma unroll
      for (int e = 0; e < 16; ++e) fsplit(fv[e], hi[e], lo[e]);
      *(uint4*)&Ash[sr * LDP + sc]     = *(uint4*)&hi[0];
      *(uint4*)&Ash[sr * LDP + sc + 8] = *(uint4*)&hi[8];
      *(uint4*)&Asl[sr * LDP + sc]     = *(uint4*)&lo[0];
      *(uint4*)&Asl[sr * LDP + sc + 8] = *(uint4*)&lo[8];
    }
    {
      const size_t off = (size_t)sr * HH + ch * 32 + sc;
      *(uint4*)&Bsh[sr * LDP + sc]     = *(const uint4*)(Bh + off);
      *(uint4*)&Bsh[sr * LDP + sc + 8] = *(const uint4*)(Bh + off + 8);
      *(uint4*)&Bsl[sr * LDP + sc]     = *(const uint4*)(Bl + off);
      *(uint4*)&Bsl[sr * LDP + sc + 8] = *(const uint4*)(Bl + off + 8);
    }
    __syncthreads();
    bhalf8 afh[4], afl[4], bfh[4], bfl[4];
#pragma unroll
    for (int i = 0; i < 4; ++i) {
      const int r = (wm + i * 16 + fr) * LDP + quad * 8;
      afh[i] = *(const bhalf8*)&Ash[r];
      afl[i] = *(const bhalf8*)&Asl[r];
    }
#pragma unroll
    for (int j = 0; j < 4; ++j) {
      const int r = (wn + j * 16 + fr) * LDP + quad * 8;
      bfh[j] = *(const bhalf8*)&Bsh[r];
      bfl[j] = *(const bhalf8*)&Bsl[r];
    }
#pragma unroll
    for (int i = 0; i < 4; ++i)
#pragma unroll
      for (int j = 0; j < 4; ++j) {
        acc[i][j] = __builtin_amdgcn_mfma_f32_16x16x32_bf16(afh[i], bfh[j], acc[i][j], 0, 0, 0);
        acc[i][j] = __builtin_amdgcn_mfma_f32_16x16x32_bf16(afl[i], bfh[j], acc[i][j], 0, 0, 0);
        acc[i][j] = __builtin_amdgcn_mfma_f32_16x16x32_bf16(afh[i], bfl[j], acc[i][j], 0, 0, 0);
      }
    __syncthreads();
  }

  const int nj[4] = {wn + fr, wn + 16 + fr, wn + 32 + fr, wn + 48 + fr};
  float c0a[4], vla[4], re0[4], re1[4];
#pragma unroll
  for (int j = 0; j < 4; ++j) {
    c0a[j] = c0v[nj[j]]; vla[j] = vl[nj[j]];
    re0[j] = rev[nj[j]]; re1[j] = rev[HH + nj[j]];
  }
#pragma unroll
  for (int i = 0; i < 4; ++i)
#pragma unroll
    for (int r = 0; r < 4; ++r) {
      const int m = row0 + wm + i * 16 + quad * 4 + r;
      const int s = m >> 6;
      const float lp = log_probs[s];
      const bool isr = (m & 63) == root_local[s];
      const size_t base = (size_t)m * HH;
#pragma unroll
      for (int j = 0; j < 4; ++j)
        Cf[base + nj[j]] = acc[i][j][r] + c0a[j] + lp * vla[j] + (isr ? re1[j] : re0[j]);
    }
}

// ---------------------------------------------------------------------------
// Final BN apply with residual; coef computed inline from stats.
// ---------------------------------------------------------------------------
__launch_bounds__(256)
__global__ void bn_apply_k(const float* __restrict__ u, float* __restrict__ h,
                           const float* __restrict__ stats,
                           const float* __restrict__ gamma, const float* __restrict__ beta) {
  size_t i4 = (size_t)(blockIdx.x * 256 + threadIdx.x) * 4;
  int c = (int)(i4 & 127);
  const float invM = 1.0f / (float)SKK;
  float sc[4], sh[4];
#pragma unroll
  for (int e = 0; e < 4; ++e) {
    const float mu = stats[c + e] * invM;
    const float var = fmaf(-mu, mu, stats[HH + c + e] * invM);
    const float s = rsqrtf(var + 1e-5f) * gamma[c + e];
    sc[e] = s; sh[e] = fmaf(-mu, s, beta[c + e]);
  }
  float4 uv = *(const float4*)(u + i4);
  float4 hv = *(const float4*)(h + i4);
  float4 o;
  o.x = fmaf(uv.x, sc[0], sh[0]) + hv.x;
  o.y = fmaf(uv.y, sc[1], sh[1]) + hv.y;
  o.z = fmaf(uv.z, sc[2], sh[2]) + hv.z;
  o.w = fmaf(uv.w, sc[3], sh[3]) + hv.w;
  *(float4*)(h + i4) = o;
}

// ---------------------------------------------------------------------------
extern "C" void kernel_launch(void* const* d_in, const int* in_sizes, int n_in,
                              void* d_out, int out_size, void* d_ws, size_t ws_size,
                              hipStream_t stream) {
  const float* x          = (const float*)d_in[0];
  const float* log_probs  = (const float*)d_in[1];
  const float* node_w     = (const float*)d_in[2];
  const float* node_b     = (const float*)d_in[3];
  const float* logp_w     = (const float*)d_in[4];
  const float* logp_b     = (const float*)d_in[5];
  const float* root_emb   = (const float*)d_in[6];
  const float* init_w     = (const float*)d_in[7];
  const float* init_b     = (const float*)d_in[8];
  const float* gin_eps    = (const float*)d_in[9];
  const float* w1         = (const float*)d_in[10];
  const float* b1         = (const float*)d_in[11];
  const float* w2         = (const float*)d_in[12];
  const float* b2         = (const float*)d_in[13];
  const float* mp2w       = (const float*)d_in[14];
  const float* mp2b       = (const float*)d_in[15];
  const float* gamma      = (const float*)d_in[16];
  const float* beta       = (const float*)d_in[17];
  const int*   nodes      = (const int*)d_in[18];
  const int*   root_local = (const int*)d_in[19];
  const int*   edge_idx   = (const int*)d_in[20];
  const int*   edge_ptr   = (const int*)d_in[21];
  float* h = (float*)d_out;   // fp32 residual stream lives in d_out

  // ---- workspace carve ----
  char* wp = (char*)d_ws;
  auto take = [&](size_t bytes) { char* p = wp; wp += (bytes + 255) & ~(size_t)255; return p; };
  ushort* zh    = (ushort*)take((size_t)SKK * HH * 2);   // 32 MB
  ushort* zl    = (ushort*)take((size_t)SKK * HH * 2);
  float*  uf    = (float*)take((size_t)SKK * HH * 4);    // 64 MB
  ushort* xah   = (ushort*)take((size_t)NN * HH * 2);
  ushort* xal   = (ushort*)take((size_t)NN * HH * 2);
  ushort* Mth   = (ushort*)take((size_t)HH * HH * 2);
  ushort* Mtl   = (ushort*)take((size_t)HH * HH * 2);
  ushort* w1th  = (ushort*)take((size_t)LLAY * HH * HH * 2);
  ushort* w1tl  = (ushort*)take((size_t)LLAY * HH * HH * 2);
  ushort* w2th  = (ushort*)take((size_t)LLAY * HH * HH * 2);
  ushort* w2tl  = (ushort*)take((size_t)LLAY * HH * HH * 2);
  ushort* mp2th = (ushort*)take((size_t)LLAY * HH * 256 * 2);
  ushort* mp2tl = (ushort*)take((size_t)LLAY * HH * 256 * 2);
  float* vl       = (float*)take(HH * 4);
  float* c0v      = (float*)take(HH * 4);
  float* rev      = (float*)take(2 * HH * 4);
  float* bn_stats = (float*)take(LLAY * 2 * HH * 4);
  int*   cnti     = (int*)take((size_t)NN * 4);
  int*   excl     = (int*)take((size_t)NBLK * 256 * 4);
  int*   bsum     = (int*)take(256 * 4);
  int*   boff     = (int*)take(256 * 4);
  int*   node_ptr = (int*)take((size_t)(NN + 1) * 4);
  int*   cur      = (int*)take((size_t)NN * 4);
  int*   rowlist  = (int*)take((size_t)SKK * 4);
  int*   row_ptr  = (int*)take((size_t)(SKK + 1) * 4);
  int*   ssrc     = (int*)take((size_t)EE * 4);

  // ---- prologue ----
  hipMemsetAsync(cnti, 0, (size_t)NN * 4, stream);
  hipMemsetAsync(cur, 0, (size_t)NN * 4, stream);
  hipMemsetAsync(bn_stats, 0, LLAY * 2 * HH * 4, stream);
  fold_M_k<<<HH, HH, 0, stream>>>(node_w, init_w, Mth, Mtl);
  fold_vec_k<<<1, HH, 0, stream>>>(init_w, logp_w, node_b, logp_b, init_b, root_emb,
                                   vl, c0v, rev);
  wconv_k<<<2560, HH, 0, stream>>>(w1, w2, mp2w, w1th, w1tl, w2th, w2tl, mp2th, mp2tl);
  count_k<<<SKK / 256, 256, 0, stream>>>(nodes, cnti);
  scan1_k<<<NBLK, 256, 0, stream>>>(cnti, excl, bsum);
  scan2_k<<<1, 256, 0, stream>>>(bsum, boff);
  scan3_k<<<NBLK, 256, 0, stream>>>(excl, boff, node_ptr);
  fill_rows_k<<<SKK / 256, 256, 0, stream>>>(nodes, node_ptr, cur, rowlist);
  presort_k<<<SS, 256, 0, stream>>>(edge_idx, edge_idx + EE, edge_ptr, row_ptr, ssrc);

  // initial h (fp32, in d_out)
  mgemm0_k<<<SKK / 128, 256, 0, stream>>>(x, Mth, Mtl, h,
                                          nodes, log_probs, root_local, vl, c0v, rev);

  for (int l = 0; l < LLAY; ++l) {
    if (l == 0) {
      gin_mega_k<true><<<SS, 256, 0, stream>>>(h, nullptr, nullptr, nullptr, nullptr,
                                               row_ptr, ssrc, gin_eps, l,
                                               w1th + (size_t)l * HH * HH,
                                               w1tl + (size_t)l * HH * HH,
                                               w2th + (size_t)l * HH * HH,
                                               w2tl + (size_t)l * HH * HH,
                                               b1 + l * HH, b2 + l * HH, zh, zl);
    } else {
      gin_mega_k<false><<<SS, 256, 0, stream>>>(h, uf, bn_stats + (l - 1) * 2 * HH,
                                                gamma + (l - 1) * HH, beta + (l - 1) * HH,
                                                row_ptr, ssrc, gin_eps, l,
                                                w1th + (size_t)l * HH * HH,
                                                w1tl + (size_t)l * HH * HH,
                                                w2th + (size_t)l * HH * HH,
                                                w2tl + (size_t)l * HH * HH,
                                                b1 + l * HH, b2 + l * HH, zh, zl);
    }
    scatter_mean_k<<<NN / 2, 256, 0, stream>>>(zh, zl, node_ptr, rowlist, xah, xal);
    mp2_k<<<SKK / 64, 256, 0, stream>>>(zh, zl, xah, xal,
                                        mp2th + (size_t)l * HH * 256,
                                        mp2tl + (size_t)l * HH * 256,
                                        mp2b + l * HH, uf, nodes,
                                        bn_stats + l * 2 * HH);
  }
  // final BN+residual apply (layer 4) -> h in d_out
  bn_apply_k<<<(SKK * HH / 4) / 256, 256, 0, stream>>>(uf, h, bn_stats + 4 * 2 * HH,
                                                       gamma + 4 * HH, beta + 4 * HH);
}

// Round 5
// 1159.803 us; speedup vs baseline: 1.0486x; 1.0486x over previous
//
#include <hip/hip_runtime.h>
#include <cstdint>

#define NN   50000
#define SS   2048
#define KSUB 64
#define HH   128
#define EE   (SS * 256)
#define SKK  (SS * KSUB)    // 131072
#define LLAY 5
#define NBLK 196            // ceil(NN/256)

typedef __attribute__((ext_vector_type(8))) short bhalf8;
typedef __attribute__((ext_vector_type(4))) float f32x4;

__device__ __forceinline__ ushort f2b(float f) {
  uint u = __builtin_bit_cast(uint, f);
  uint r = (u + 0x7FFFu + ((u >> 16) & 1u)) >> 16;
  return (ushort)r;
}
__device__ __forceinline__ float b2f(ushort u) {
  uint v = ((uint)u) << 16;
  return __builtin_bit_cast(float, v);
}
// split fp32 -> (hi, lo) bf16 pair; hi + lo ~= f with ~2^-18 residual
__device__ __forceinline__ void fsplit(float f, ushort& hi, ushort& lo) {
  hi = f2b(f);
  lo = f2b(f - b2f(hi));
}
// byte offset into a [64][128]-short LDS tile, T2 XOR swizzle (row stride 256B)
__device__ __forceinline__ int zoff(int row, int col) {
  return row * 256 + (((col * 2) & 255) ^ ((row & 7) << 4));
}

// ---------------------------------------------------------------------------
// Fold node_proj through init_proj; emit split bf16 B^T layout [n][c]
// ---------------------------------------------------------------------------
__global__ void fold_M_k(const float* __restrict__ Wn, const float* __restrict__ Wi,
                         ushort* __restrict__ Mth, ushort* __restrict__ Mtl) {
  int c = blockIdx.x, n = threadIdx.x;
  float s = 0.f;
  for (int k = 0; k < HH; ++k) s = fmaf(Wn[c * HH + k], Wi[k * HH + n], s);
  ushort hi, lo; fsplit(s, hi, lo);
  Mth[n * HH + c] = hi; Mtl[n * HH + c] = lo;
}

__global__ void fold_vec_k(const float* __restrict__ Wi, const float* __restrict__ wl,
                           const float* __restrict__ bnb, const float* __restrict__ blb,
                           const float* __restrict__ bi, const float* __restrict__ remb,
                           float* __restrict__ vl, float* __restrict__ c0,
                           float* __restrict__ rev) {
  int n = threadIdx.x;
  float svl = 0.f, sc0 = bi[n], r0 = 0.f, r1 = 0.f;
  for (int k = 0; k < HH; ++k) {
    svl = fmaf(wl[k], Wi[(HH + k) * HH + n], svl);
    sc0 = fmaf(bnb[k], Wi[k * HH + n], sc0);
    sc0 = fmaf(blb[k], Wi[(HH + k) * HH + n], sc0);
    r0  = fmaf(remb[k],      Wi[(2 * HH + k) * HH + n], r0);
    r1  = fmaf(remb[HH + k], Wi[(2 * HH + k) * HH + n], r1);
  }
  vl[n] = svl; c0[n] = sc0; rev[n] = r0; rev[HH + n] = r1;
}

// ---------------------------------------------------------------------------
// Transpose+convert all layer weights to split bf16 B^T layout (one launch).
// ---------------------------------------------------------------------------
__global__ void wconv_k(const float* __restrict__ w1, const float* __restrict__ w2,
                        const float* __restrict__ mp2w,
                        ushort* __restrict__ w1th, ushort* __restrict__ w1tl,
                        ushort* __restrict__ w2th, ushort* __restrict__ w2tl,
                        ushort* __restrict__ mp2th, ushort* __restrict__ mp2tl) {
  int b = blockIdx.x, n = threadIdx.x;
  ushort hi, lo;
  if (b < 640) {
    int l = b >> 7, k = b & 127;
    fsplit(w1[((size_t)l * HH + k) * HH + n], hi, lo);
    w1th[((size_t)l * HH + n) * HH + k] = hi;
    w1tl[((size_t)l * HH + n) * HH + k] = lo;
  } else if (b < 1280) {
    int bb = b - 640; int l = bb >> 7, k = bb & 127;
    fsplit(w2[((size_t)l * HH + k) * HH + n], hi, lo);
    w2th[((size_t)l * HH + n) * HH + k] = hi;
    w2tl[((size_t)l * HH + n) * HH + k] = lo;
  } else {
    int bb = b - 1280; int l = bb >> 8, k = bb & 255;
    fsplit(mp2w[((size_t)l * 256 + k) * HH + n], hi, lo);
    mp2th[((size_t)l * HH + n) * 256 + k] = hi;
    mp2tl[((size_t)l * HH + n) * 256 + k] = lo;
  }
}

// ---------------------------------------------------------------------------
// Node-CSR construction: count -> exclusive scan -> fill
// ---------------------------------------------------------------------------
__global__ void count_k(const int* __restrict__ idc, int* __restrict__ cnt) {
  int i = blockIdx.x * 256 + threadIdx.x;
  if (i < SKK) atomicAdd(&cnt[idc[i]], 1);
}

__global__ void scan1_k(const int* __restrict__ cnt, int* __restrict__ excl,
                        int* __restrict__ bsum) {
  __shared__ int sh[256];
  const int tid = threadIdx.x;
  const int i = blockIdx.x * 256 + tid;
  int v = (i < NN) ? cnt[i] : 0;
  sh[tid] = v;
  __syncthreads();
#pragma unroll
  for (int off = 1; off < 256; off <<= 1) {
    int t = (tid >= off) ? sh[tid - off] : 0;
    __syncthreads();
    sh[tid] += t;
    __syncthreads();
  }
  excl[i] = sh[tid] - v;
  if (tid == 255) bsum[blockIdx.x] = sh[tid];
}

__global__ void scan2_k(int* __restrict__ bsum, int* __restrict__ boff) {
  __shared__ int sh[256];
  const int tid = threadIdx.x;
  int v = (tid < NBLK) ? bsum[tid] : 0;
  sh[tid] = v;
  __syncthreads();
#pragma unroll
  for (int off = 1; off < 256; off <<= 1) {
    int t = (tid >= off) ? sh[tid - off] : 0;
    __syncthreads();
    sh[tid] += t;
    __syncthreads();
  }
  boff[tid] = sh[tid] - v;
}

__global__ void scan3_k(const int* __restrict__ excl, const int* __restrict__ boff,
                        int* __restrict__ node_ptr) {
  int i = blockIdx.x * 256 + threadIdx.x;
  if (i < NN) node_ptr[i] = excl[i] + boff[blockIdx.x];
  if (i == 0) node_ptr[NN] = SKK;
}

__global__ void fill_rows_k(const int* __restrict__ idc, const int* __restrict__ node_ptr,
                            int* __restrict__ cur, int* __restrict__ rowlist) {
  int i = blockIdx.x * 256 + threadIdx.x;
  if (i < SKK) {
    int id = idc[i];
    int pos = atomicAdd(&cur[id], 1);
    rowlist[node_ptr[id] + pos] = i;
  }
}

// ---------------------------------------------------------------------------
// Cross-subgraph scatter-mean as a GATHER (split in, fp32 acc, split out)
// ---------------------------------------------------------------------------
__launch_bounds__(256)
__global__ void scatter_mean_k(const ushort* __restrict__ zh, const ushort* __restrict__ zl,
                               const int* __restrict__ node_ptr,
                               const int* __restrict__ rowlist,
                               ushort* __restrict__ xah, ushort* __restrict__ xal) {
  const int tid = threadIdx.x;
  const int n = blockIdx.x * 2 + (tid >> 7);
  if (n >= NN) return;
  const int c = tid & 127;
  const int p0 = node_ptr[n], p1 = node_ptr[n + 1];
  float s = 0.f;
  for (int p = p0; p < p1; ++p) {
    const size_t off = (size_t)rowlist[p] * HH + c;
    s += b2f(zh[off]) + b2f(zl[off]);
  }
  const float inv = 1.0f / (float)max(p1 - p0, 1);
  ushort hi, lo; fsplit(s * inv, hi, lo);
  xah[(size_t)n * HH + c] = hi;
  xal[(size_t)n * HH + c] = lo;
}

// ---------------------------------------------------------------------------
// Per-subgraph counting sort of edges by dst -> CSR
// ---------------------------------------------------------------------------
__launch_bounds__(256)
__global__ void presort_k(const int* __restrict__ e_src, const int* __restrict__ e_dst,
                          const int* __restrict__ edge_ptr, int* __restrict__ row_ptr,
                          int* __restrict__ ssrc) {
  __shared__ int cnt[KSUB];
  __shared__ int base[KSUB];
  __shared__ int cur[KSUB];
  const int s = blockIdx.x, tid = threadIdx.x;
  const int p0 = edge_ptr[s], p1 = edge_ptr[s + 1];
  if (tid < KSUB) cnt[tid] = 0;
  __syncthreads();
  for (int e = p0 + tid; e < p1; e += 256) atomicAdd(&cnt[e_dst[e]], 1);
  __syncthreads();
  if (tid == 0) {
    int a = 0;
    for (int d = 0; d < KSUB; ++d) { base[d] = a; a += cnt[d]; }
  }
  __syncthreads();
  if (tid < KSUB) { row_ptr[s * KSUB + tid] = p0 + base[tid]; cur[tid] = base[tid]; }
  if (s == 0 && tid == 0) row_ptr[SS * KSUB] = edge_ptr[SS];
  __syncthreads();
  for (int e = p0 + tid; e < p1; e += 256) {
    int d = e_dst[e];
    int pos = atomicAdd(&cur[d], 1);
    ssrc[p0 + pos] = e_src[e];
  }
}

// ---------------------------------------------------------------------------
// MEGA kernel: per subgraph (64 rows):
//   phase A: h_new = bn(uf) + h_old (residual) [skip BN if FIRST];
//            BN coef computed INLINE from stats (replaces bn_finalize_k);
//            write h_new to global AND keep fp32 tile in LDS
//   phase B: GIN aggregation z_agg = (1+eps)h_new + sum_src h_new  (regs)
//   phase C: split z_agg -> swizzled bf16 LDS tile Z (aliases h tile)
//   MLP1:    t = relu(Z @ W1 + b1) -> swizzled LDS tile T (aliases Z)
//   MLP2:    z = T @ W2 + b2       -> global zh/zl (split)
// ---------------------------------------------------------------------------
template <bool FIRST>
__launch_bounds__(256, 4)
__global__ void gin_mega_k(float* __restrict__ h, const float* __restrict__ uf,
                           const float* __restrict__ stats,
                           const float* __restrict__ gamma, const float* __restrict__ beta,
                           const int* __restrict__ row_ptr, const int* __restrict__ ssrc,
                           const float* __restrict__ gin_eps, const int layer,
                           const ushort* __restrict__ B1h, const ushort* __restrict__ B1l,
                           const ushort* __restrict__ B2h, const ushort* __restrict__ B2l,
                           const float* __restrict__ bias1, const float* __restrict__ bias2,
                           ushort* __restrict__ zh, ushort* __restrict__ zl) {
  constexpr int LDH = 132;
  __shared__ __align__(16) char smem[KSUB * LDH * 4];   // 33792 B, phase-aliased
  float*  hl = (float*)smem;                 // [64][132] fp32 (phases A,B)
  ushort* Zh = (ushort*)smem;                // [64][128] swizzled (phases C..MLP2)
  ushort* Zl = (ushort*)(smem + KSUB * HH * 2);
  const int s = blockIdx.x, tid = threadIdx.x;
  const size_t base = (size_t)s * KSUB * HH;

  // ---- phase A (BN coef inline; c constant across 'it' since 1024 % 128 == 0) ----
  float csc[4], csh[4];
  const int cb = (tid * 4) & 127;
  if constexpr (!FIRST) {
    const float invM = 1.0f / (float)SKK;
#pragma unroll
    for (int e = 0; e < 4; ++e) {
      const float mu = stats[cb + e] * invM;
      const float var = fmaf(-mu, mu, stats[HH + cb + e] * invM);
      const float sc = rsqrtf(var + 1e-5f) * gamma[cb + e];
      csc[e] = sc; csh[e] = fmaf(-mu, sc, beta[cb + e]);
    }
  }
#pragma unroll
  for (int it = 0; it < 8; ++it) {
    const int idx = it * 1024 + tid * 4;
    const int m = idx >> 7, c = idx & 127;
    float4 hv = *(const float4*)&h[base + idx];
    if constexpr (!FIRST) {
      float4 u4 = *(const float4*)&uf[base + idx];
      hv.x += fmaf(u4.x, csc[0], csh[0]);
      hv.y += fmaf(u4.y, csc[1], csh[1]);
      hv.z += fmaf(u4.z, csc[2], csh[2]);
      hv.w += fmaf(u4.w, csc[3], csh[3]);
      *(float4*)&h[base + idx] = hv;
    }
    *(float4*)&hl[m * LDH + c] = hv;
  }
  __syncthreads();

  // ---- phase B: aggregation ----
  const float ep1 = 1.0f + gin_eps[layer];
  const int d = tid >> 2, cg = (tid & 3) * 32;
  const int g = s * KSUB + d;
  const int e0 = row_ptr[g], e1 = row_ptr[g + 1];
  float a[32];
  {
    const float* hp0 = &hl[d * LDH + cg];
#pragma unroll
    for (int j = 0; j < 8; ++j) {
      float4 v = *(const float4*)(hp0 + 4 * j);
      a[4 * j + 0] = ep1 * v.x; a[4 * j + 1] = ep1 * v.y;
      a[4 * j + 2] = ep1 * v.z; a[4 * j + 3] = ep1 * v.w;
    }
    for (int e = e0; e < e1; ++e) {
      const float* hp = &hl[ssrc[e] * LDH + cg];
#pragma unroll
      for (int j = 0; j < 8; ++j) {
        float4 v = *(const float4*)(hp + 4 * j);
        a[4 * j + 0] += v.x; a[4 * j + 1] += v.y;
        a[4 * j + 2] += v.z; a[4 * j + 3] += v.w;
      }
    }
  }
  __syncthreads();          // all hl reads done (Z aliases hl)

  // ---- phase C: split z_agg into swizzled LDS tile ----
#pragma unroll
  for (int q = 0; q < 4; ++q) {
    ushort th[8], tl[8];
#pragma unroll
    for (int e = 0; e < 8; ++e) fsplit(a[q * 8 + e], th[e], tl[e]);
    const int o = zoff(d, cg + q * 8);
    *(uint4*)((char*)Zh + o) = *(uint4*)th;
    *(uint4*)((char*)Zl + o) = *(uint4*)tl;
  }
  __syncthreads();

  // ---- MLP GEMMs ----
  const int lane = tid & 63, wv = tid >> 6;
  const int fr = lane & 15, quad = lane >> 4;
  const int nj0 = wv * 32 + fr, nj1 = nj0 + 16;

  f32x4 acc[4][2];
#pragma unroll
  for (int i = 0; i < 4; ++i) { acc[i][0] = (f32x4){0,0,0,0}; acc[i][1] = (f32x4){0,0,0,0}; }

  // MLP1: t = relu(Z @ W1 + b1)
#pragma unroll
  for (int ch = 0; ch < 4; ++ch) {
    bhalf8 afh[4], afl[4], bfh[2], bfl[2];
#pragma unroll
    for (int i = 0; i < 4; ++i) {
      const int o = zoff(i * 16 + fr, ch * 32 + quad * 8);
      afh[i] = *(const bhalf8*)((const char*)Zh + o);
      afl[i] = *(const bhalf8*)((const char*)Zl + o);
    }
#pragma unroll
    for (int j = 0; j < 2; ++j) {
      const size_t off = (size_t)(wv * 32 + j * 16 + fr) * HH + ch * 32 + quad * 8;
      bfh[j] = *(const bhalf8*)(B1h + off);
      bfl[j] = *(const bhalf8*)(B1l + off);
    }
#pragma unroll
    for (int i = 0; i < 4; ++i)
#pragma unroll
      for (int j = 0; j < 2; ++j) {
        acc[i][j] = __builtin_amdgcn_mfma_f32_16x16x32_bf16(afh[i], bfh[j], acc[i][j], 0, 0, 0);
        acc[i][j] = __builtin_amdgcn_mfma_f32_16x16x32_bf16(afl[i], bfh[j], acc[i][j], 0, 0, 0);
        acc[i][j] = __builtin_amdgcn_mfma_f32_16x16x32_bf16(afh[i], bfl[j], acc[i][j], 0, 0, 0);
      }
  }
  __syncthreads();          // all Z reads done (T aliases Z)

  // epilogue 1: T = relu(acc + b1), split, into swizzled LDS
  {
    const float b10 = bias1[nj0], b11 = bias1[nj1];
#pragma unroll
    for (int i = 0; i < 4; ++i)
#pragma unroll
      for (int r = 0; r < 4; ++r) {
        const int row = i * 16 + quad * 4 + r;
        const float o0 = fmaxf(acc[i][0][r] + b10, 0.f);
        const float o1 = fmaxf(acc[i][1][r] + b11, 0.f);
        ushort h0, l0, h1, l1; fsplit(o0, h0, l0); fsplit(o1, h1, l1);
        *(ushort*)((char*)Zh + zoff(row, nj0)) = h0;
        *(ushort*)((char*)Zl + zoff(row, nj0)) = l0;
        *(ushort*)((char*)Zh + zoff(row, nj1)) = h1;
        *(ushort*)((char*)Zl + zoff(row, nj1)) = l1;
      }
  }
  __syncthreads();

  // MLP2: z = T @ W2 + b2
#pragma unroll
  for (int i = 0; i < 4; ++i) { acc[i][0] = (f32x4){0,0,0,0}; acc[i][1] = (f32x4){0,0,0,0}; }
#pragma unroll
  for (int ch = 0; ch < 4; ++ch) {
    bhalf8 afh[4], afl[4], bfh[2], bfl[2];
#pragma unroll
    for (int i = 0; i < 4; ++i) {
      const int o = zoff(i * 16 + fr, ch * 32 + quad * 8);
      afh[i] = *(const bhalf8*)((const char*)Zh + o);
      afl[i] = *(const bhalf8*)((const char*)Zl + o);
    }
#pragma unroll
    for (int j = 0; j < 2; ++j) {
      const size_t off = (size_t)(wv * 32 + j * 16 + fr) * HH + ch * 32 + quad * 8;
      bfh[j] = *(const bhalf8*)(B2h + off);
      bfl[j] = *(const bhalf8*)(B2l + off);
    }
#pragma unroll
    for (int i = 0; i < 4; ++i)
#pragma unroll
      for (int j = 0; j < 2; ++j) {
        acc[i][j] = __builtin_amdgcn_mfma_f32_16x16x32_bf16(afh[i], bfh[j], acc[i][j], 0, 0, 0);
        acc[i][j] = __builtin_amdgcn_mfma_f32_16x16x32_bf16(afl[i], bfh[j], acc[i][j], 0, 0, 0);
        acc[i][j] = __builtin_amdgcn_mfma_f32_16x16x32_bf16(afh[i], bfl[j], acc[i][j], 0, 0, 0);
      }
  }

  // epilogue 2: z -> global (split)
  {
    const float b20 = bias2[nj0], b21 = bias2[nj1];
#pragma unroll
    for (int i = 0; i < 4; ++i)
#pragma unroll
      for (int r = 0; r < 4; ++r) {
        const int row = i * 16 + quad * 4 + r;
        const size_t gb = base + (size_t)row * HH;
        const float o0 = acc[i][0][r] + b20;
        const float o1 = acc[i][1][r] + b21;
        ushort h0, l0, h1, l1; fsplit(o0, h0, l0); fsplit(o1, h1, l1);
        zh[gb + nj0] = h0; zl[gb + nj0] = l0;
        zh[gb + nj1] = h1; zl[gb + nj1] = l1;
      }
  }
}

// ---------------------------------------------------------------------------
// MP-2 GEMM: 64-row blocks, grid SKK/64 = 2048, 4 blocks/CU.
// u = relu([z | xa[idc]] @ W + b), W in [n][256] split layout.
// B fragments batch-loaded into REGISTERS before each half's staging barrier
// (T14 issue-early): the A-stage vmcnt drain retires them, so the MFMA loop
// runs on LDS + regs only — no in-loop global traffic (round-4 lesson).
// ---------------------------------------------------------------------------
__launch_bounds__(256, 4)
__global__ void mp2_k(const ushort* __restrict__ zh, const ushort* __restrict__ zl,
                      const ushort* __restrict__ xah, const ushort* __restrict__ xal,
                      const ushort* __restrict__ Bh, const ushort* __restrict__ Bl,
                      const float* __restrict__ bias, float* __restrict__ uf,
                      const int* __restrict__ idc, float* __restrict__ stats) {
  __shared__ __align__(16) char smem[KSUB * HH * 2 * 2];   // 32 KB: Th,Tl
  __shared__ float sred[2 * HH];
  ushort* Th = (ushort*)smem;
  ushort* Tl = (ushort*)(smem + KSUB * HH * 2);
  const int tid = threadIdx.x;
  const int row0 = blockIdx.x * 64;
  const int sr = tid >> 2, qq = tid & 3;      // staging: row, 32-short chunk
  const int lane = tid & 63, wv = tid >> 6;
  const int fr = lane & 15, quad = lane >> 4;
  const int nj0 = wv * 32 + fr, nj1 = nj0 + 16;

  f32x4 acc[4][2];
#pragma unroll
  for (int i = 0; i < 4; ++i) { acc[i][0] = (f32x4){0,0,0,0}; acc[i][1] = (f32x4){0,0,0,0}; }

#pragma unroll
  for (int half = 0; half < 2; ++half) {
    // ---- batch-issue ALL B fragments for this half into registers ----
    bhalf8 bfh[4][2], bfl[4][2];
#pragma unroll
    for (int ch = 0; ch < 4; ++ch)
#pragma unroll
      for (int j = 0; j < 2; ++j) {
        const size_t off = (size_t)(wv * 32 + j * 16 + fr) * 256 + half * 128 + ch * 32 + quad * 8;
        bfh[ch][j] = *(const bhalf8*)(Bh + off);
        bfl[ch][j] = *(const bhalf8*)(Bl + off);
      }
    // ---- stage A half-tile (swizzled); its vmcnt drain also retires B ----
    {
      size_t src;
      const ushort *ah, *al;
      if (half == 0) {
        src = (size_t)(row0 + sr) * HH + qq * 32;
        ah = zh; al = zl;
      } else {
        src = (size_t)idc[row0 + sr] * HH + qq * 32;
        ah = xah; al = xal;
      }
#pragma unroll
      for (int q = 0; q < 4; ++q) {
        const int o = zoff(sr, qq * 32 + q * 8);
        *(uint4*)((char*)Th + o) = *(const uint4*)(ah + src + q * 8);
        *(uint4*)((char*)Tl + o) = *(const uint4*)(al + src + q * 8);
      }
    }
    __syncthreads();
    // ---- GEMM half: acc += T @ W[:, half*128 : half*128+128] (LDS + regs) ----
#pragma unroll
    for (int ch = 0; ch < 4; ++ch) {
      bhalf8 afh[4], afl[4];
#pragma unroll
      for (int i = 0; i < 4; ++i) {
        const int o = zoff(i * 16 + fr, ch * 32 + quad * 8);
        afh[i] = *(const bhalf8*)((const char*)Th + o);
        afl[i] = *(const bhalf8*)((const char*)Tl + o);
      }
#pragma unroll
      for (int i = 0; i < 4; ++i)
#pragma unroll
        for (int j = 0; j < 2; ++j) {
          acc[i][j] = __builtin_amdgcn_mfma_f32_16x16x32_bf16(afh[i], bfh[ch][j], acc[i][j], 0, 0, 0);
          acc[i][j] = __builtin_amdgcn_mfma_f32_16x16x32_bf16(afl[i], bfh[ch][j], acc[i][j], 0, 0, 0);
          acc[i][j] = __builtin_amdgcn_mfma_f32_16x16x32_bf16(afh[i], bfl[ch][j], acc[i][j], 0, 0, 0);
        }
    }
    if (half == 0) __syncthreads();   // tile reused for the gather half
  }

  // ---- epilogue: relu + bias, uf write, BN stats ----
  const float b0 = bias[nj0], b1 = bias[nj1];
  float psum0 = 0.f, psq0 = 0.f, psum1 = 0.f, psq1 = 0.f;
#pragma unroll
  for (int i = 0; i < 4; ++i)
#pragma unroll
    for (int r = 0; r < 4; ++r) {
      const int row = i * 16 + quad * 4 + r;
      const size_t gb = (size_t)(row0 + row) * HH;
      const float o0 = fmaxf(acc[i][0][r] + b0, 0.f);
      const float o1 = fmaxf(acc[i][1][r] + b1, 0.f);
      uf[gb + nj0] = o0;
      uf[gb + nj1] = o1;
      psum0 += o0; psq0 += o0 * o0;
      psum1 += o1; psq1 += o1 * o1;
    }
  sred[tid] = 0.f;
  __syncthreads();
  atomicAdd(&sred[nj0], psum0);
  atomicAdd(&sred[HH + nj0], psq0);
  atomicAdd(&sred[nj1], psum1);
  atomicAdd(&sred[HH + nj1], psq1);
  __syncthreads();
  unsafeAtomicAdd(&stats[tid], sred[tid]);
}

// ---------------------------------------------------------------------------
// Split-bf16 MFMA GEMM (round-0 verified LDS-staged version) — MODE 0 only.
// ---------------------------------------------------------------------------
__launch_bounds__(256, 2)
__global__ void mgemm0_k(const float* __restrict__ Afp,
                         const ushort* __restrict__ Bh, const ushort* __restrict__ Bl,
                         float* __restrict__ Cf,
                         const int* __restrict__ idc, const float* __restrict__ log_probs,
                         const int* __restrict__ root_local, const float* __restrict__ vl,
                         const float* __restrict__ c0v, const float* __restrict__ rev) {
  constexpr int LDP = 40;
  __shared__ __align__(16) ushort Ash[128 * LDP];
  __shared__ __align__(16) ushort Asl[128 * LDP];
  __shared__ __align__(16) ushort Bsh[128 * LDP];
  __shared__ __align__(16) ushort Bsl[128 * LDP];
  const int tid = threadIdx.x;
  const int row0 = blockIdx.x * 128;
  const int lane = tid & 63, wv = tid >> 6;
  const int wm = (wv >> 1) * 64, wn = (wv & 1) * 64;
  const int fr = lane & 15, quad = lane >> 4;
  const int sr = tid >> 1;
  const int sc = (tid & 1) * 16;

  f32x4 acc[4][4];
#pragma unroll
  for (int i = 0; i < 4; ++i)
#pragma unroll
    for (int j = 0; j < 4; ++j) acc[i][j] = (f32x4){0.f, 0.f, 0.f, 0.f};

  for (int ch = 0; ch < 4; ++ch) {
    {
      const float* src = Afp + (size_t)idc[row0 + sr] * HH + ch * 32 + sc;
      float fv[16];
      *(float4*)&fv[0]  = *(const float4*)(src);
      *(float4*)&fv[4]  = *(const float4*)(src + 4);
      *(float4*)&fv[8]  = *(const float4*)(src + 8);
      *(float4*)&fv[12] = *(const float4*)(src + 12);
      ushort hi[16], lo[16];
#pragma unroll
      for (int e = 0; e < 16; ++e) fsplit(fv[e], hi[e], lo[e]);
      *(uint4*)&Ash[sr * LDP + sc]     = *(uint4*)&hi[0];
      *(uint4*)&Ash[sr * LDP + sc + 8] = *(uint4*)&hi[8];
      *(uint4*)&Asl[sr * LDP + sc]     = *(uint4*)&lo[0];
      *(uint4*)&Asl[sr * LDP + sc + 8] = *(uint4*)&lo[8];
    }
    {
      const size_t off = (size_t)sr * HH + ch * 32 + sc;
      *(uint4*)&Bsh[sr * LDP + sc]     = *(const uint4*)(Bh + off);
      *(uint4*)&Bsh[sr * LDP + sc + 8] = *(const uint4*)(Bh + off + 8);
      *(uint4*)&Bsl[sr * LDP + sc]     = *(const uint4*)(Bl + off);
      *(uint4*)&Bsl[sr * LDP + sc + 8] = *(const uint4*)(Bl + off + 8);
    }
    __syncthreads();
    bhalf8 afh[4], afl[4], bfh[4], bfl[4];
#pragma unroll
    for (int i = 0; i < 4; ++i) {
      const int r = (wm + i * 16 + fr) * LDP + quad * 8;
      afh[i] = *(const bhalf8*)&Ash[r];
      afl[i] = *(const bhalf8*)&Asl[r];
    }
#pragma unroll
    for (int j = 0; j < 4; ++j) {
      const int r = (wn + j * 16 + fr) * LDP + quad * 8;
      bfh[j] = *(const bhalf8*)&Bsh[r];
      bfl[j] = *(const bhalf8*)&Bsl[r];
    }
#pragma unroll
    for (int i = 0; i < 4; ++i)
#pragma unroll
      for (int j = 0; j < 4; ++j) {
        acc[i][j] = __builtin_amdgcn_mfma_f32_16x16x32_bf16(afh[i], bfh[j], acc[i][j], 0, 0, 0);
        acc[i][j] = __builtin_amdgcn_mfma_f32_16x16x32_bf16(afl[i], bfh[j], acc[i][j], 0, 0, 0);
        acc[i][j] = __builtin_amdgcn_mfma_f32_16x16x32_bf16(afh[i], bfl[j], acc[i][j], 0, 0, 0);
      }
    __syncthreads();
  }

  const int nj[4] = {wn + fr, wn + 16 + fr, wn + 32 + fr, wn + 48 + fr};
  float c0a[4], vla[4], re0[4], re1[4];
#pragma unroll
  for (int j = 0; j < 4; ++j) {
    c0a[j] = c0v[nj[j]]; vla[j] = vl[nj[j]];
    re0[j] = rev[nj[j]]; re1[j] = rev[HH + nj[j]];
  }
#pragma unroll
  for (int i = 0; i < 4; ++i)
#pragma unroll
    for (int r = 0; r < 4; ++r) {
      const int m = row0 + wm + i * 16 + quad * 4 + r;
      const int s = m >> 6;
      const float lp = log_probs[s];
      const bool isr = (m & 63) == root_local[s];
      const size_t base = (size_t)m * HH;
#pragma unroll
      for (int j = 0; j < 4; ++j)
        Cf[base + nj[j]] = acc[i][j][r] + c0a[j] + lp * vla[j] + (isr ? re1[j] : re0[j]);
    }
}

// ---------------------------------------------------------------------------
// Final BN apply with residual; coef computed inline from stats.
// ---------------------------------------------------------------------------
__launch_bounds__(256)
__global__ void bn_apply_k(const float* __restrict__ u, float* __restrict__ h,
                           const float* __restrict__ stats,
                           const float* __restrict__ gamma, const float* __restrict__ beta) {
  size_t i4 = (size_t)(blockIdx.x * 256 + threadIdx.x) * 4;
  int c = (int)(i4 & 127);
  const float invM = 1.0f / (float)SKK;
  float sc[4], sh[4];
#pragma unroll
  for (int e = 0; e < 4; ++e) {
    const float mu = stats[c + e] * invM;
    const float var = fmaf(-mu, mu, stats[HH + c + e] * invM);
    const float s = rsqrtf(var + 1e-5f) * gamma[c + e];
    sc[e] = s; sh[e] = fmaf(-mu, s, beta[c + e]);
  }
  float4 uv = *(const float4*)(u + i4);
  float4 hv = *(const float4*)(h + i4);
  float4 o;
  o.x = fmaf(uv.x, sc[0], sh[0]) + hv.x;
  o.y = fmaf(uv.y, sc[1], sh[1]) + hv.y;
  o.z = fmaf(uv.z, sc[2], sh[2]) + hv.z;
  o.w = fmaf(uv.w, sc[3], sh[3]) + hv.w;
  *(float4*)(h + i4) = o;
}

// ---------------------------------------------------------------------------
extern "C" void kernel_launch(void* const* d_in, const int* in_sizes, int n_in,
                              void* d_out, int out_size, void* d_ws, size_t ws_size,
                              hipStream_t stream) {
  const float* x          = (const float*)d_in[0];
  const float* log_probs  = (const float*)d_in[1];
  const float* node_w     = (const float*)d_in[2];
  const float* node_b     = (const float*)d_in[3];
  const float* logp_w     = (const float*)d_in[4];
  const float* logp_b     = (const float*)d_in[5];
  const float* root_emb   = (const float*)d_in[6];
  const float* init_w     = (const float*)d_in[7];
  const float* init_b     = (const float*)d_in[8];
  const float* gin_eps    = (const float*)d_in[9];
  const float* w1         = (const float*)d_in[10];
  const float* b1         = (const float*)d_in[11];
  const float* w2         = (const float*)d_in[12];
  const float* b2         = (const float*)d_in[13];
  const float* mp2w       = (const float*)d_in[14];
  const float* mp2b       = (const float*)d_in[15];
  const float* gamma      = (const float*)d_in[16];
  const float* beta       = (const float*)d_in[17];
  const int*   nodes      = (const int*)d_in[18];
  const int*   root_local = (const int*)d_in[19];
  const int*   edge_idx   = (const int*)d_in[20];
  const int*   edge_ptr   = (const int*)d_in[21];
  float* h = (float*)d_out;   // fp32 residual stream lives in d_out

  // ---- workspace carve ----
  char* wp = (char*)d_ws;
  auto take = [&](size_t bytes) { char* p = wp; wp += (bytes + 255) & ~(size_t)255; return p; };
  ushort* zh    = (ushort*)take((size_t)SKK * HH * 2);   // 32 MB
  ushort* zl    = (ushort*)take((size_t)SKK * HH * 2);
  float*  uf    = (float*)take((size_t)SKK * HH * 4);    // 64 MB
  ushort* xah   = (ushort*)take((size_t)NN * HH * 2);
  ushort* xal   = (ushort*)take((size_t)NN * HH * 2);
  ushort* Mth   = (ushort*)take((size_t)HH * HH * 2);
  ushort* Mtl   = (ushort*)take((size_t)HH * HH * 2);
  ushort* w1th  = (ushort*)take((size_t)LLAY * HH * HH * 2);
  ushort* w1tl  = (ushort*)take((size_t)LLAY * HH * HH * 2);
  ushort* w2th  = (ushort*)take((size_t)LLAY * HH * HH * 2);
  ushort* w2tl  = (ushort*)take((size_t)LLAY * HH * HH * 2);
  ushort* mp2th = (ushort*)take((size_t)LLAY * HH * 256 * 2);
  ushort* mp2tl = (ushort*)take((size_t)LLAY * HH * 256 * 2);
  float* vl       = (float*)take(HH * 4);
  float* c0v      = (float*)take(HH * 4);
  float* rev      = (float*)take(2 * HH * 4);
  float* bn_stats = (float*)take(LLAY * 2 * HH * 4);
  int*   cnti     = (int*)take((size_t)NN * 4);
  int*   excl     = (int*)take((size_t)NBLK * 256 * 4);
  int*   bsum     = (int*)take(256 * 4);
  int*   boff     = (int*)take(256 * 4);
  int*   node_ptr = (int*)take((size_t)(NN + 1) * 4);
  int*   cur      = (int*)take((size_t)NN * 4);
  int*   rowlist  = (int*)take((size_t)SKK * 4);
  int*   row_ptr  = (int*)take((size_t)(SKK + 1) * 4);
  int*   ssrc     = (int*)take((size_t)EE * 4);

  // ---- prologue ----
  hipMemsetAsync(cnti, 0, (size_t)NN * 4, stream);
  hipMemsetAsync(cur, 0, (size_t)NN * 4, stream);
  hipMemsetAsync(bn_stats, 0, LLAY * 2 * HH * 4, stream);
  fold_M_k<<<HH, HH, 0, stream>>>(node_w, init_w, Mth, Mtl);
  fold_vec_k<<<1, HH, 0, stream>>>(init_w, logp_w, node_b, logp_b, init_b, root_emb,
                                   vl, c0v, rev);
  wconv_k<<<2560, HH, 0, stream>>>(w1, w2, mp2w, w1th, w1tl, w2th, w2tl, mp2th, mp2tl);
  count_k<<<SKK / 256, 256, 0, stream>>>(nodes, cnti);
  scan1_k<<<NBLK, 256, 0, stream>>>(cnti, excl, bsum);
  scan2_k<<<1, 256, 0, stream>>>(bsum, boff);
  scan3_k<<<NBLK, 256, 0, stream>>>(excl, boff, node_ptr);
  fill_rows_k<<<SKK / 256, 256, 0, stream>>>(nodes, node_ptr, cur, rowlist);
  presort_k<<<SS, 256, 0, stream>>>(edge_idx, edge_idx + EE, edge_ptr, row_ptr, ssrc);

  // initial h (fp32, in d_out)
  mgemm0_k<<<SKK / 128, 256, 0, stream>>>(x, Mth, Mtl, h,
                                          nodes, log_probs, root_local, vl, c0v, rev);

  for (int l = 0; l < LLAY; ++l) {
    if (l == 0) {
      gin_mega_k<true><<<SS, 256, 0, stream>>>(h, nullptr, nullptr, nullptr, nullptr,
                                               row_ptr, ssrc, gin_eps, l,
                                               w1th + (size_t)l * HH * HH,
                                               w1tl + (size_t)l * HH * HH,
                                               w2th + (size_t)l * HH * HH,
                                               w2tl + (size_t)l * HH * HH,
                                               b1 + l * HH, b2 + l * HH, zh, zl);
    } else {
      gin_mega_k<false><<<SS, 256, 0, stream>>>(h, uf, bn_stats + (l - 1) * 2 * HH,
                                                gamma + (l - 1) * HH, beta + (l - 1) * HH,
                                                row_ptr, ssrc, gin_eps, l,
                                                w1th + (size_t)l * HH * HH,
                                                w1tl + (size_t)l * HH * HH,
                                                w2th + (size_t)l * HH * HH,
                                                w2tl + (size_t)l * HH * HH,
                                                b1 + l * HH, b2 + l * HH, zh, zl);
    }
    scatter_mean_k<<<NN / 2, 256, 0, stream>>>(zh, zl, node_ptr, rowlist, xah, xal);
    mp2_k<<<SKK / 64, 256, 0, stream>>>(zh, zl, xah, xal,
                                        mp2th + (size_t)l * HH * 256,
                                        mp2tl + (size_t)l * HH * 256,
                                        mp2b + l * HH, uf, nodes,
                                        bn_stats + l * 2 * HH);
  }
  // final BN+residual apply (layer 4) -> h in d_out
  bn_apply_k<<<(SKK * HH / 4) / 256, 256, 0, stream>>>(uf, h, bn_stats + 4 * 2 * HH,
                                                       gamma + 4 * HH, beta + 4 * HH);
}

// Round 6
// 1097.334 us; speedup vs baseline: 1.1083x; 1.0569x over previous
//
#include <hip/hip_runtime.h>
#include <cstdint>

#define NN   50000
#define SS   2048
#define KSUB 64
#define HH   128
#define EE   (SS * 256)
#define SKK  (SS * KSUB)    // 131072
#define LLAY 5
#define NBLK 196            // ceil(NN/256)

typedef __attribute__((ext_vector_type(8))) short bhalf8;
typedef __attribute__((ext_vector_type(4))) float f32x4;

__device__ __forceinline__ ushort f2b(float f) {
  uint u = __builtin_bit_cast(uint, f);
  uint r = (u + 0x7FFFu + ((u >> 16) & 1u)) >> 16;
  return (ushort)r;
}
__device__ __forceinline__ float b2f(ushort u) {
  uint v = ((uint)u) << 16;
  return __builtin_bit_cast(float, v);
}
// split fp32 -> (hi, lo) bf16 pair; hi + lo ~= f with ~2^-18 residual
__device__ __forceinline__ void fsplit(float f, ushort& hi, ushort& lo) {
  hi = f2b(f);
  lo = f2b(f - b2f(hi));
}
// byte offset into a [64][128]-short LDS tile, T2 XOR swizzle (row stride 256B)
__device__ __forceinline__ int zoff(int row, int col) {
  return row * 256 + (((col * 2) & 255) ^ ((row & 7) << 4));
}

// ---------------------------------------------------------------------------
// Fold node_proj through init_proj; emit split bf16 B^T layout [n][c]
// ---------------------------------------------------------------------------
__global__ void fold_M_k(const float* __restrict__ Wn, const float* __restrict__ Wi,
                         ushort* __restrict__ Mth, ushort* __restrict__ Mtl) {
  int c = blockIdx.x, n = threadIdx.x;
  float s = 0.f;
  for (int k = 0; k < HH; ++k) s = fmaf(Wn[c * HH + k], Wi[k * HH + n], s);
  ushort hi, lo; fsplit(s, hi, lo);
  Mth[n * HH + c] = hi; Mtl[n * HH + c] = lo;
}

__global__ void fold_vec_k(const float* __restrict__ Wi, const float* __restrict__ wl,
                           const float* __restrict__ bnb, const float* __restrict__ blb,
                           const float* __restrict__ bi, const float* __restrict__ remb,
                           float* __restrict__ vl, float* __restrict__ c0,
                           float* __restrict__ rev) {
  int n = threadIdx.x;
  float svl = 0.f, sc0 = bi[n], r0 = 0.f, r1 = 0.f;
  for (int k = 0; k < HH; ++k) {
    svl = fmaf(wl[k], Wi[(HH + k) * HH + n], svl);
    sc0 = fmaf(bnb[k], Wi[k * HH + n], sc0);
    sc0 = fmaf(blb[k], Wi[(HH + k) * HH + n], sc0);
    r0  = fmaf(remb[k],      Wi[(2 * HH + k) * HH + n], r0);
    r1  = fmaf(remb[HH + k], Wi[(2 * HH + k) * HH + n], r1);
  }
  vl[n] = svl; c0[n] = sc0; rev[n] = r0; rev[HH + n] = r1;
}

// ---------------------------------------------------------------------------
// Transpose+convert all layer weights to split bf16 B^T layout (one launch).
// ---------------------------------------------------------------------------
__global__ void wconv_k(const float* __restrict__ w1, const float* __restrict__ w2,
                        const float* __restrict__ mp2w,
                        ushort* __restrict__ w1th, ushort* __restrict__ w1tl,
                        ushort* __restrict__ w2th, ushort* __restrict__ w2tl,
                        ushort* __restrict__ mp2th, ushort* __restrict__ mp2tl) {
  int b = blockIdx.x, n = threadIdx.x;
  ushort hi, lo;
  if (b < 640) {
    int l = b >> 7, k = b & 127;
    fsplit(w1[((size_t)l * HH + k) * HH + n], hi, lo);
    w1th[((size_t)l * HH + n) * HH + k] = hi;
    w1tl[((size_t)l * HH + n) * HH + k] = lo;
  } else if (b < 1280) {
    int bb = b - 640; int l = bb >> 7, k = bb & 127;
    fsplit(w2[((size_t)l * HH + k) * HH + n], hi, lo);
    w2th[((size_t)l * HH + n) * HH + k] = hi;
    w2tl[((size_t)l * HH + n) * HH + k] = lo;
  } else {
    int bb = b - 1280; int l = bb >> 8, k = bb & 255;
    fsplit(mp2w[((size_t)l * 256 + k) * HH + n], hi, lo);
    mp2th[((size_t)l * HH + n) * 256 + k] = hi;
    mp2tl[((size_t)l * HH + n) * 256 + k] = lo;
  }
}

// ---------------------------------------------------------------------------
// Node-CSR construction: count -> exclusive scan -> fill
// ---------------------------------------------------------------------------
__global__ void count_k(const int* __restrict__ idc, int* __restrict__ cnt) {
  int i = blockIdx.x * 256 + threadIdx.x;
  if (i < SKK) atomicAdd(&cnt[idc[i]], 1);
}

__global__ void scan1_k(const int* __restrict__ cnt, int* __restrict__ excl,
                        int* __restrict__ bsum) {
  __shared__ int sh[256];
  const int tid = threadIdx.x;
  const int i = blockIdx.x * 256 + tid;
  int v = (i < NN) ? cnt[i] : 0;
  sh[tid] = v;
  __syncthreads();
#pragma unroll
  for (int off = 1; off < 256; off <<= 1) {
    int t = (tid >= off) ? sh[tid - off] : 0;
    __syncthreads();
    sh[tid] += t;
    __syncthreads();
  }
  excl[i] = sh[tid] - v;
  if (tid == 255) bsum[blockIdx.x] = sh[tid];
}

__global__ void scan2_k(int* __restrict__ bsum, int* __restrict__ boff) {
  __shared__ int sh[256];
  const int tid = threadIdx.x;
  int v = (tid < NBLK) ? bsum[tid] : 0;
  sh[tid] = v;
  __syncthreads();
#pragma unroll
  for (int off = 1; off < 256; off <<= 1) {
    int t = (tid >= off) ? sh[tid - off] : 0;
    __syncthreads();
    sh[tid] += t;
    __syncthreads();
  }
  boff[tid] = sh[tid] - v;
}

__global__ void scan3_k(const int* __restrict__ excl, const int* __restrict__ boff,
                        int* __restrict__ node_ptr) {
  int i = blockIdx.x * 256 + threadIdx.x;
  if (i < NN) node_ptr[i] = excl[i] + boff[blockIdx.x];
  if (i == 0) node_ptr[NN] = SKK;
}

__global__ void fill_rows_k(const int* __restrict__ idc, const int* __restrict__ node_ptr,
                            int* __restrict__ cur, int* __restrict__ rowlist) {
  int i = blockIdx.x * 256 + threadIdx.x;
  if (i < SKK) {
    int id = idc[i];
    int pos = atomicAdd(&cur[id], 1);
    rowlist[node_ptr[id] + pos] = i;
  }
}

// ---------------------------------------------------------------------------
// Cross-subgraph scatter-mean as a GATHER (split in, fp32 acc, split out)
// ---------------------------------------------------------------------------
__launch_bounds__(256)
__global__ void scatter_mean_k(const ushort* __restrict__ zh, const ushort* __restrict__ zl,
                               const int* __restrict__ node_ptr,
                               const int* __restrict__ rowlist,
                               ushort* __restrict__ xah, ushort* __restrict__ xal) {
  const int tid = threadIdx.x;
  const int n = blockIdx.x * 2 + (tid >> 7);
  if (n >= NN) return;
  const int c = tid & 127;
  const int p0 = node_ptr[n], p1 = node_ptr[n + 1];
  float s = 0.f;
  for (int p = p0; p < p1; ++p) {
    const size_t off = (size_t)rowlist[p] * HH + c;
    s += b2f(zh[off]) + b2f(zl[off]);
  }
  const float inv = 1.0f / (float)max(p1 - p0, 1);
  ushort hi, lo; fsplit(s * inv, hi, lo);
  xah[(size_t)n * HH + c] = hi;
  xal[(size_t)n * HH + c] = lo;
}

// ---------------------------------------------------------------------------
// Per-subgraph counting sort of edges by dst -> CSR
// ---------------------------------------------------------------------------
__launch_bounds__(256)
__global__ void presort_k(const int* __restrict__ e_src, const int* __restrict__ e_dst,
                          const int* __restrict__ edge_ptr, int* __restrict__ row_ptr,
                          int* __restrict__ ssrc) {
  __shared__ int cnt[KSUB];
  __shared__ int base[KSUB];
  __shared__ int cur[KSUB];
  const int s = blockIdx.x, tid = threadIdx.x;
  const int p0 = edge_ptr[s], p1 = edge_ptr[s + 1];
  if (tid < KSUB) cnt[tid] = 0;
  __syncthreads();
  for (int e = p0 + tid; e < p1; e += 256) atomicAdd(&cnt[e_dst[e]], 1);
  __syncthreads();
  if (tid == 0) {
    int a = 0;
    for (int d = 0; d < KSUB; ++d) { base[d] = a; a += cnt[d]; }
  }
  __syncthreads();
  if (tid < KSUB) { row_ptr[s * KSUB + tid] = p0 + base[tid]; cur[tid] = base[tid]; }
  if (s == 0 && tid == 0) row_ptr[SS * KSUB] = edge_ptr[SS];
  __syncthreads();
  for (int e = p0 + tid; e < p1; e += 256) {
    int d = e_dst[e];
    int pos = atomicAdd(&cur[d], 1);
    ssrc[p0 + pos] = e_src[e];
  }
}

// ---------------------------------------------------------------------------
// MEGA kernel: per subgraph (64 rows):
//   phase A: h_new = bn(uf) + h_old (residual) [skip BN if FIRST];
//            BN coef computed INLINE from stats (replaces bn_finalize_k);
//            write h_new to global AND keep fp32 tile in LDS
//   phase B: GIN aggregation z_agg = (1+eps)h_new + sum_src h_new  (regs)
//   phase C: split z_agg -> swizzled bf16 LDS tile Z (aliases h tile)
//   MLP1:    t = relu(Z @ W1 + b1) -> swizzled LDS tile T (aliases Z)
//   MLP2:    z = T @ W2 + b2       -> global zh/zl (split)
// ---------------------------------------------------------------------------
template <bool FIRST>
__launch_bounds__(256, 4)
__global__ void gin_mega_k(float* __restrict__ h, const float* __restrict__ uf,
                           const float* __restrict__ stats,
                           const float* __restrict__ gamma, const float* __restrict__ beta,
                           const int* __restrict__ row_ptr, const int* __restrict__ ssrc,
                           const float* __restrict__ gin_eps, const int layer,
                           const ushort* __restrict__ B1h, const ushort* __restrict__ B1l,
                           const ushort* __restrict__ B2h, const ushort* __restrict__ B2l,
                           const float* __restrict__ bias1, const float* __restrict__ bias2,
                           ushort* __restrict__ zh, ushort* __restrict__ zl) {
  constexpr int LDH = 132;
  __shared__ __align__(16) char smem[KSUB * LDH * 4];   // 33792 B, phase-aliased
  float*  hl = (float*)smem;                 // [64][132] fp32 (phases A,B)
  ushort* Zh = (ushort*)smem;                // [64][128] swizzled (phases C..MLP2)
  ushort* Zl = (ushort*)(smem + KSUB * HH * 2);
  const int s = blockIdx.x, tid = threadIdx.x;
  const size_t base = (size_t)s * KSUB * HH;

  // ---- phase A (BN coef inline; c constant across 'it' since 1024 % 128 == 0) ----
  float csc[4], csh[4];
  const int cb = (tid * 4) & 127;
  if constexpr (!FIRST) {
    const float invM = 1.0f / (float)SKK;
#pragma unroll
    for (int e = 0; e < 4; ++e) {
      const float mu = stats[cb + e] * invM;
      const float var = fmaf(-mu, mu, stats[HH + cb + e] * invM);
      const float sc = rsqrtf(var + 1e-5f) * gamma[cb + e];
      csc[e] = sc; csh[e] = fmaf(-mu, sc, beta[cb + e]);
    }
  }
#pragma unroll
  for (int it = 0; it < 8; ++it) {
    const int idx = it * 1024 + tid * 4;
    const int m = idx >> 7, c = idx & 127;
    float4 hv = *(const float4*)&h[base + idx];
    if constexpr (!FIRST) {
      float4 u4 = *(const float4*)&uf[base + idx];
      hv.x += fmaf(u4.x, csc[0], csh[0]);
      hv.y += fmaf(u4.y, csc[1], csh[1]);
      hv.z += fmaf(u4.z, csc[2], csh[2]);
      hv.w += fmaf(u4.w, csc[3], csh[3]);
      *(float4*)&h[base + idx] = hv;
    }
    *(float4*)&hl[m * LDH + c] = hv;
  }
  __syncthreads();

  // ---- phase B: aggregation ----
  const float ep1 = 1.0f + gin_eps[layer];
  const int d = tid >> 2, cg = (tid & 3) * 32;
  const int g = s * KSUB + d;
  const int e0 = row_ptr[g], e1 = row_ptr[g + 1];
  float a[32];
  {
    const float* hp0 = &hl[d * LDH + cg];
#pragma unroll
    for (int j = 0; j < 8; ++j) {
      float4 v = *(const float4*)(hp0 + 4 * j);
      a[4 * j + 0] = ep1 * v.x; a[4 * j + 1] = ep1 * v.y;
      a[4 * j + 2] = ep1 * v.z; a[4 * j + 3] = ep1 * v.w;
    }
    for (int e = e0; e < e1; ++e) {
      const float* hp = &hl[ssrc[e] * LDH + cg];
#pragma unroll
      for (int j = 0; j < 8; ++j) {
        float4 v = *(const float4*)(hp + 4 * j);
        a[4 * j + 0] += v.x; a[4 * j + 1] += v.y;
        a[4 * j + 2] += v.z; a[4 * j + 3] += v.w;
      }
    }
  }
  __syncthreads();          // all hl reads done (Z aliases hl)

  // ---- phase C: split z_agg into swizzled LDS tile ----
#pragma unroll
  for (int q = 0; q < 4; ++q) {
    ushort th[8], tl[8];
#pragma unroll
    for (int e = 0; e < 8; ++e) fsplit(a[q * 8 + e], th[e], tl[e]);
    const int o = zoff(d, cg + q * 8);
    *(uint4*)((char*)Zh + o) = *(uint4*)th;
    *(uint4*)((char*)Zl + o) = *(uint4*)tl;
  }
  __syncthreads();

  // ---- MLP GEMMs ----
  const int lane = tid & 63, wv = tid >> 6;
  const int fr = lane & 15, quad = lane >> 4;
  const int nj0 = wv * 32 + fr, nj1 = nj0 + 16;

  f32x4 acc[4][2];
#pragma unroll
  for (int i = 0; i < 4; ++i) { acc[i][0] = (f32x4){0,0,0,0}; acc[i][1] = (f32x4){0,0,0,0}; }

  // MLP1: t = relu(Z @ W1 + b1)
#pragma unroll
  for (int ch = 0; ch < 4; ++ch) {
    bhalf8 afh[4], afl[4], bfh[2], bfl[2];
#pragma unroll
    for (int i = 0; i < 4; ++i) {
      const int o = zoff(i * 16 + fr, ch * 32 + quad * 8);
      afh[i] = *(const bhalf8*)((const char*)Zh + o);
      afl[i] = *(const bhalf8*)((const char*)Zl + o);
    }
#pragma unroll
    for (int j = 0; j < 2; ++j) {
      const size_t off = (size_t)(wv * 32 + j * 16 + fr) * HH + ch * 32 + quad * 8;
      bfh[j] = *(const bhalf8*)(B1h + off);
      bfl[j] = *(const bhalf8*)(B1l + off);
    }
#pragma unroll
    for (int i = 0; i < 4; ++i)
#pragma unroll
      for (int j = 0; j < 2; ++j) {
        acc[i][j] = __builtin_amdgcn_mfma_f32_16x16x32_bf16(afh[i], bfh[j], acc[i][j], 0, 0, 0);
        acc[i][j] = __builtin_amdgcn_mfma_f32_16x16x32_bf16(afl[i], bfh[j], acc[i][j], 0, 0, 0);
        acc[i][j] = __builtin_amdgcn_mfma_f32_16x16x32_bf16(afh[i], bfl[j], acc[i][j], 0, 0, 0);
      }
  }
  __syncthreads();          // all Z reads done (T aliases Z)

  // epilogue 1: T = relu(acc + b1), split, into swizzled LDS
  {
    const float b10 = bias1[nj0], b11 = bias1[nj1];
#pragma unroll
    for (int i = 0; i < 4; ++i)
#pragma unroll
      for (int r = 0; r < 4; ++r) {
        const int row = i * 16 + quad * 4 + r;
        const float o0 = fmaxf(acc[i][0][r] + b10, 0.f);
        const float o1 = fmaxf(acc[i][1][r] + b11, 0.f);
        ushort h0, l0, h1, l1; fsplit(o0, h0, l0); fsplit(o1, h1, l1);
        *(ushort*)((char*)Zh + zoff(row, nj0)) = h0;
        *(ushort*)((char*)Zl + zoff(row, nj0)) = l0;
        *(ushort*)((char*)Zh + zoff(row, nj1)) = h1;
        *(ushort*)((char*)Zl + zoff(row, nj1)) = l1;
      }
  }
  __syncthreads();

  // MLP2: z = T @ W2 + b2
#pragma unroll
  for (int i = 0; i < 4; ++i) { acc[i][0] = (f32x4){0,0,0,0}; acc[i][1] = (f32x4){0,0,0,0}; }
#pragma unroll
  for (int ch = 0; ch < 4; ++ch) {
    bhalf8 afh[4], afl[4], bfh[2], bfl[2];
#pragma unroll
    for (int i = 0; i < 4; ++i) {
      const int o = zoff(i * 16 + fr, ch * 32 + quad * 8);
      afh[i] = *(const bhalf8*)((const char*)Zh + o);
      afl[i] = *(const bhalf8*)((const char*)Zl + o);
    }
#pragma unroll
    for (int j = 0; j < 2; ++j) {
      const size_t off = (size_t)(wv * 32 + j * 16 + fr) * HH + ch * 32 + quad * 8;
      bfh[j] = *(const bhalf8*)(B2h + off);
      bfl[j] = *(const bhalf8*)(B2l + off);
    }
#pragma unroll
    for (int i = 0; i < 4; ++i)
#pragma unroll
      for (int j = 0; j < 2; ++j) {
        acc[i][j] = __builtin_amdgcn_mfma_f32_16x16x32_bf16(afh[i], bfh[j], acc[i][j], 0, 0, 0);
        acc[i][j] = __builtin_amdgcn_mfma_f32_16x16x32_bf16(afl[i], bfh[j], acc[i][j], 0, 0, 0);
        acc[i][j] = __builtin_amdgcn_mfma_f32_16x16x32_bf16(afh[i], bfl[j], acc[i][j], 0, 0, 0);
      }
  }

  // epilogue 2: z -> global (split)
  {
    const float b20 = bias2[nj0], b21 = bias2[nj1];
#pragma unroll
    for (int i = 0; i < 4; ++i)
#pragma unroll
      for (int r = 0; r < 4; ++r) {
        const int row = i * 16 + quad * 4 + r;
        const size_t gb = base + (size_t)row * HH;
        const float o0 = acc[i][0][r] + b20;
        const float o1 = acc[i][1][r] + b21;
        ushort h0, l0, h1, l1; fsplit(o0, h0, l0); fsplit(o1, h1, l1);
        zh[gb + nj0] = h0; zl[gb + nj0] = l0;
        zh[gb + nj1] = h1; zl[gb + nj1] = l1;
      }
  }
}

// ---------------------------------------------------------------------------
// MP-2 GEMM: verified round-0 mgemm_k<3> structure (128-row tiles, LDS-staged
// A and B, LDP=40) + T14 issue-early prefetch: chunk ch+1's global loads are
// issued right after the barrier that opens chunk ch's MFMA phase, so HBM
// latency overlaps MFMA+barrier+ds_write instead of serializing.
// 3 blocks/CU (120KB LDS), prefetch regs +32 VGPR over the base's 76.
// ---------------------------------------------------------------------------
__launch_bounds__(256, 3)
__global__ void mp2_k(const ushort* __restrict__ Ah, const ushort* __restrict__ Al,
                      const ushort* __restrict__ A2h, const ushort* __restrict__ A2l,
                      const ushort* __restrict__ Bh, const ushort* __restrict__ Bl,
                      const float* __restrict__ bias, float* __restrict__ Cf,
                      const int* __restrict__ idc, float* __restrict__ stats) {
  constexpr int LDP = 40;   // LDS row stride in shorts
  __shared__ __align__(16) ushort Ash[128 * LDP];
  __shared__ __align__(16) ushort Asl[128 * LDP];
  __shared__ __align__(16) ushort Bsh[128 * LDP];
  __shared__ __align__(16) ushort Bsl[128 * LDP];
  const int tid = threadIdx.x;
  const int row0 = blockIdx.x * 128;
  const int lane = tid & 63, wv = tid >> 6;
  const int wm = (wv >> 1) * 64, wn = (wv & 1) * 64;
  const int fr = lane & 15, quad = lane >> 4;
  const int sr = tid >> 1;            // staging row 0..127
  const int sc = (tid & 1) * 16;      // staging short-offset {0,16}
  const int grow = idc[row0 + sr];    // gather row for K-half 2 (hoisted)

  f32x4 acc[4][4];
#pragma unroll
  for (int i = 0; i < 4; ++i)
#pragma unroll
    for (int j = 0; j < 4; ++j) acc[i][j] = (f32x4){0.f, 0.f, 0.f, 0.f};

  uint4 pa0, pa1, pa2, pa3, pb0, pb1, pb2, pb3;   // prefetch registers
  auto LA = [&](int ch) {
    const ushort *sh_, *sl_;
    if (ch >= 4) {
      const size_t off = (size_t)grow * HH + (ch - 4) * 32 + sc;
      sh_ = A2h + off; sl_ = A2l + off;
    } else {
      const size_t off = (size_t)(row0 + sr) * HH + ch * 32 + sc;
      sh_ = Ah + off; sl_ = Al + off;
    }
    pa0 = *(const uint4*)(sh_);     pa1 = *(const uint4*)(sh_ + 8);
    pa2 = *(const uint4*)(sl_);     pa3 = *(const uint4*)(sl_ + 8);
  };
  auto LB = [&](int ch) {
    const size_t off = (size_t)sr * 256 + ch * 32 + sc;
    pb0 = *(const uint4*)(Bh + off); pb1 = *(const uint4*)(Bh + off + 8);
    pb2 = *(const uint4*)(Bl + off); pb3 = *(const uint4*)(Bl + off + 8);
  };

  LA(0); LB(0);
#pragma unroll
  for (int ch = 0; ch < 8; ++ch) {
    // ---- write prefetched chunk to LDS ----
    *(uint4*)&Ash[sr * LDP + sc]     = pa0;
    *(uint4*)&Ash[sr * LDP + sc + 8] = pa1;
    *(uint4*)&Asl[sr * LDP + sc]     = pa2;
    *(uint4*)&Asl[sr * LDP + sc + 8] = pa3;
    *(uint4*)&Bsh[sr * LDP + sc]     = pb0;
    *(uint4*)&Bsh[sr * LDP + sc + 8] = pb1;
    *(uint4*)&Bsl[sr * LDP + sc]     = pb2;
    *(uint4*)&Bsl[sr * LDP + sc + 8] = pb3;
    __syncthreads();
    // ---- issue next chunk's global loads (fly during MFMA) ----
    if (ch < 7) { LA(ch + 1); LB(ch + 1); }
    // ---- one K=32 MFMA step, bf16x3 ----
    bhalf8 afh[4], afl[4], bfh[4], bfl[4];
#pragma unroll
    for (int i = 0; i < 4; ++i) {
      const int r = (wm + i * 16 + fr) * LDP + quad * 8;
      afh[i] = *(const bhalf8*)&Ash[r];
      afl[i] = *(const bhalf8*)&Asl[r];
    }
#pragma unroll
    for (int j = 0; j < 4; ++j) {
      const int r = (wn + j * 16 + fr) * LDP + quad * 8;
      bfh[j] = *(const bhalf8*)&Bsh[r];
      bfl[j] = *(const bhalf8*)&Bsl[r];
    }
#pragma unroll
    for (int i = 0; i < 4; ++i)
#pragma unroll
      for (int j = 0; j < 4; ++j) {
        acc[i][j] = __builtin_amdgcn_mfma_f32_16x16x32_bf16(afh[i], bfh[j], acc[i][j], 0, 0, 0);
        acc[i][j] = __builtin_amdgcn_mfma_f32_16x16x32_bf16(afl[i], bfh[j], acc[i][j], 0, 0, 0);
        acc[i][j] = __builtin_amdgcn_mfma_f32_16x16x32_bf16(afh[i], bfl[j], acc[i][j], 0, 0, 0);
      }
    __syncthreads();
  }

  // ---- epilogue: relu + bias, uf write, BN stats ----
  const int nj[4] = {wn + fr, wn + 16 + fr, wn + 32 + fr, wn + 48 + fr};
  float bb[4];
#pragma unroll
  for (int j = 0; j < 4; ++j) bb[j] = bias[nj[j]];
  float psum[4] = {0.f, 0.f, 0.f, 0.f}, psq[4] = {0.f, 0.f, 0.f, 0.f};
#pragma unroll
  for (int i = 0; i < 4; ++i)
#pragma unroll
    for (int r = 0; r < 4; ++r) {
      const int m = row0 + wm + i * 16 + quad * 4 + r;
      const size_t base = (size_t)m * HH;
#pragma unroll
      for (int j = 0; j < 4; ++j) {
        float o = fmaxf(acc[i][j][r] + bb[j], 0.f);
        Cf[base + nj[j]] = o;
        psum[j] += o; psq[j] += o * o;
      }
    }
  float* ssum = (float*)Ash;      // dead past last barrier
  float* ssq = ssum + HH;
  if (tid < HH) { ssum[tid] = 0.f; ssq[tid] = 0.f; }
  __syncthreads();
#pragma unroll
  for (int j = 0; j < 4; ++j) {
    atomicAdd(&ssum[nj[j]], psum[j]);
    atomicAdd(&ssq[nj[j]], psq[j]);
  }
  __syncthreads();
  if (tid < HH) {
    unsafeAtomicAdd(&stats[tid], ssum[tid]);
    unsafeAtomicAdd(&stats[HH + tid], ssq[tid]);
  }
}

// ---------------------------------------------------------------------------
// Split-bf16 MFMA GEMM (round-0 verified LDS-staged version) — MODE 0 only.
// ---------------------------------------------------------------------------
__launch_bounds__(256, 2)
__global__ void mgemm0_k(const float* __restrict__ Afp,
                         const ushort* __restrict__ Bh, const ushort* __restrict__ Bl,
                         float* __restrict__ Cf,
                         const int* __restrict__ idc, const float* __restrict__ log_probs,
                         const int* __restrict__ root_local, const float* __restrict__ vl,
                         const float* __restrict__ c0v, const float* __restrict__ rev) {
  constexpr int LDP = 40;
  __shared__ __align__(16) ushort Ash[128 * LDP];
  __shared__ __align__(16) ushort Asl[128 * LDP];
  __shared__ __align__(16) ushort Bsh[128 * LDP];
  __shared__ __align__(16) ushort Bsl[128 * LDP];
  const int tid = threadIdx.x;
  const int row0 = blockIdx.x * 128;
  const int lane = tid & 63, wv = tid >> 6;
  const int wm = (wv >> 1) * 64, wn = (wv & 1) * 64;
  const int fr = lane & 15, quad = lane >> 4;
  const int sr = tid >> 1;
  const int sc = (tid & 1) * 16;

  f32x4 acc[4][4];
#pragma unroll
  for (int i = 0; i < 4; ++i)
#pragma unroll
    for (int j = 0; j < 4; ++j) acc[i][j] = (f32x4){0.f, 0.f, 0.f, 0.f};

  for (int ch = 0; ch < 4; ++ch) {
    {
      const float* src = Afp + (size_t)idc[row0 + sr] * HH + ch * 32 + sc;
      float fv[16];
      *(float4*)&fv[0]  = *(const float4*)(src);
      *(float4*)&fv[4]  = *(const float4*)(src + 4);
      *(float4*)&fv[8]  = *(const float4*)(src + 8);
      *(float4*)&fv[12] = *(const float4*)(src + 12);
      ushort hi[16], lo[16];
#pragma unroll
      for (int e = 0; e < 16; ++e) fsplit(fv[e], hi[e], lo[e]);
      *(uint4*)&Ash[sr * LDP + sc]     = *(uint4*)&hi[0];
      *(uint4*)&Ash[sr * LDP + sc + 8] = *(uint4*)&hi[8];
      *(uint4*)&Asl[sr * LDP + sc]     = *(uint4*)&lo[0];
      *(uint4*)&Asl[sr * LDP + sc + 8] = *(uint4*)&lo[8];
    }
    {
      const size_t off = (size_t)sr * HH + ch * 32 + sc;
      *(uint4*)&Bsh[sr * LDP + sc]     = *(const uint4*)(Bh + off);
      *(uint4*)&Bsh[sr * LDP + sc + 8] = *(const uint4*)(Bh + off + 8);
      *(uint4*)&Bsl[sr * LDP + sc]     = *(const uint4*)(Bl + off);
      *(uint4*)&Bsl[sr * LDP + sc + 8] = *(const uint4*)(Bl + off + 8);
    }
    __syncthreads();
    bhalf8 afh[4], afl[4], bfh[4], bfl[4];
#pragma unroll
    for (int i = 0; i < 4; ++i) {
      const int r = (wm + i * 16 + fr) * LDP + quad * 8;
      afh[i] = *(const bhalf8*)&Ash[r];
      afl[i] = *(const bhalf8*)&Asl[r];
    }
#pragma unroll
    for (int j = 0; j < 4; ++j) {
      const int r = (wn + j * 16 + fr) * LDP + quad * 8;
      bfh[j] = *(const bhalf8*)&Bsh[r];
      bfl[j] = *(const bhalf8*)&Bsl[r];
    }
#pragma unroll
    for (int i = 0; i < 4; ++i)
#pragma unroll
      for (int j = 0; j < 4; ++j) {
        acc[i][j] = __builtin_amdgcn_mfma_f32_16x16x32_bf16(afh[i], bfh[j], acc[i][j], 0, 0, 0);
        acc[i][j] = __builtin_amdgcn_mfma_f32_16x16x32_bf16(afl[i], bfh[j], acc[i][j], 0, 0, 0);
        acc[i][j] = __builtin_amdgcn_mfma_f32_16x16x32_bf16(afh[i], bfl[j], acc[i][j], 0, 0, 0);
      }
    __syncthreads();
  }

  const int nj[4] = {wn + fr, wn + 16 + fr, wn + 32 + fr, wn + 48 + fr};
  float c0a[4], vla[4], re0[4], re1[4];
#pragma unroll
  for (int j = 0; j < 4; ++j) {
    c0a[j] = c0v[nj[j]]; vla[j] = vl[nj[j]];
    re0[j] = rev[nj[j]]; re1[j] = rev[HH + nj[j]];
  }
#pragma unroll
  for (int i = 0; i < 4; ++i)
#pragma unroll
    for (int r = 0; r < 4; ++r) {
      const int m = row0 + wm + i * 16 + quad * 4 + r;
      const int s = m >> 6;
      const float lp = log_probs[s];
      const bool isr = (m & 63) == root_local[s];
      const size_t base = (size_t)m * HH;
#pragma unroll
      for (int j = 0; j < 4; ++j)
        Cf[base + nj[j]] = acc[i][j][r] + c0a[j] + lp * vla[j] + (isr ? re1[j] : re0[j]);
    }
}

// ---------------------------------------------------------------------------
// Final BN apply with residual; coef computed inline from stats.
// ---------------------------------------------------------------------------
__launch_bounds__(256)
__global__ void bn_apply_k(const float* __restrict__ u, float* __restrict__ h,
                           const float* __restrict__ stats,
                           const float* __restrict__ gamma, const float* __restrict__ beta) {
  size_t i4 = (size_t)(blockIdx.x * 256 + threadIdx.x) * 4;
  int c = (int)(i4 & 127);
  const float invM = 1.0f / (float)SKK;
  float sc[4], sh[4];
#pragma unroll
  for (int e = 0; e < 4; ++e) {
    const float mu = stats[c + e] * invM;
    const float var = fmaf(-mu, mu, stats[HH + c + e] * invM);
    const float s = rsqrtf(var + 1e-5f) * gamma[c + e];
    sc[e] = s; sh[e] = fmaf(-mu, s, beta[c + e]);
  }
  float4 uv = *(const float4*)(u + i4);
  float4 hv = *(const float4*)(h + i4);
  float4 o;
  o.x = fmaf(uv.x, sc[0], sh[0]) + hv.x;
  o.y = fmaf(uv.y, sc[1], sh[1]) + hv.y;
  o.z = fmaf(uv.z, sc[2], sh[2]) + hv.z;
  o.w = fmaf(uv.w, sc[3], sh[3]) + hv.w;
  *(float4*)(h + i4) = o;
}

// ---------------------------------------------------------------------------
extern "C" void kernel_launch(void* const* d_in, const int* in_sizes, int n_in,
                              void* d_out, int out_size, void* d_ws, size_t ws_size,
                              hipStream_t stream) {
  const float* x          = (const float*)d_in[0];
  const float* log_probs  = (const float*)d_in[1];
  const float* node_w     = (const float*)d_in[2];
  const float* node_b     = (const float*)d_in[3];
  const float* logp_w     = (const float*)d_in[4];
  const float* logp_b     = (const float*)d_in[5];
  const float* root_emb   = (const float*)d_in[6];
  const float* init_w     = (const float*)d_in[7];
  const float* init_b     = (const float*)d_in[8];
  const float* gin_eps    = (const float*)d_in[9];
  const float* w1         = (const float*)d_in[10];
  const float* b1         = (const float*)d_in[11];
  const float* w2         = (const float*)d_in[12];
  const float* b2         = (const float*)d_in[13];
  const float* mp2w       = (const float*)d_in[14];
  const float* mp2b       = (const float*)d_in[15];
  const float* gamma      = (const float*)d_in[16];
  const float* beta       = (const float*)d_in[17];
  const int*   nodes      = (const int*)d_in[18];
  const int*   root_local = (const int*)d_in[19];
  const int*   edge_idx   = (const int*)d_in[20];
  const int*   edge_ptr   = (const int*)d_in[21];
  float* h = (float*)d_out;   // fp32 residual stream lives in d_out

  // ---- workspace carve ----
  char* wp = (char*)d_ws;
  auto take = [&](size_t bytes) { char* p = wp; wp += (bytes + 255) & ~(size_t)255; return p; };
  ushort* zh    = (ushort*)take((size_t)SKK * HH * 2);   // 32 MB
  ushort* zl    = (ushort*)take((size_t)SKK * HH * 2);
  float*  uf    = (float*)take((size_t)SKK * HH * 4);    // 64 MB
  ushort* xah   = (ushort*)take((size_t)NN * HH * 2);
  ushort* xal   = (ushort*)take((size_t)NN * HH * 2);
  ushort* Mth   = (ushort*)take((size_t)HH * HH * 2);
  ushort* Mtl   = (ushort*)take((size_t)HH * HH * 2);
  ushort* w1th  = (ushort*)take((size_t)LLAY * HH * HH * 2);
  ushort* w1tl  = (ushort*)take((size_t)LLAY * HH * HH * 2);
  ushort* w2th  = (ushort*)take((size_t)LLAY * HH * HH * 2);
  ushort* w2tl  = (ushort*)take((size_t)LLAY * HH * HH * 2);
  ushort* mp2th = (ushort*)take((size_t)LLAY * HH * 256 * 2);
  ushort* mp2tl = (ushort*)take((size_t)LLAY * HH * 256 * 2);
  float* vl       = (float*)take(HH * 4);
  float* c0v      = (float*)take(HH * 4);
  float* rev      = (float*)take(2 * HH * 4);
  float* bn_stats = (float*)take(LLAY * 2 * HH * 4);
  int*   cnti     = (int*)take((size_t)NN * 4);
  int*   excl     = (int*)take((size_t)NBLK * 256 * 4);
  int*   bsum     = (int*)take(256 * 4);
  int*   boff     = (int*)take(256 * 4);
  int*   node_ptr = (int*)take((size_t)(NN + 1) * 4);
  int*   cur      = (int*)take((size_t)NN * 4);
  int*   rowlist  = (int*)take((size_t)SKK * 4);
  int*   row_ptr  = (int*)take((size_t)(SKK + 1) * 4);
  int*   ssrc     = (int*)take((size_t)EE * 4);

  // ---- prologue ----
  hipMemsetAsync(cnti, 0, (size_t)NN * 4, stream);
  hipMemsetAsync(cur, 0, (size_t)NN * 4, stream);
  hipMemsetAsync(bn_stats, 0, LLAY * 2 * HH * 4, stream);
  fold_M_k<<<HH, HH, 0, stream>>>(node_w, init_w, Mth, Mtl);
  fold_vec_k<<<1, HH, 0, stream>>>(init_w, logp_w, node_b, logp_b, init_b, root_emb,
                                   vl, c0v, rev);
  wconv_k<<<2560, HH, 0, stream>>>(w1, w2, mp2w, w1th, w1tl, w2th, w2tl, mp2th, mp2tl);
  count_k<<<SKK / 256, 256, 0, stream>>>(nodes, cnti);
  scan1_k<<<NBLK, 256, 0, stream>>>(cnti, excl, bsum);
  scan2_k<<<1, 256, 0, stream>>>(bsum, boff);
  scan3_k<<<NBLK, 256, 0, stream>>>(excl, boff, node_ptr);
  fill_rows_k<<<SKK / 256, 256, 0, stream>>>(nodes, node_ptr, cur, rowlist);
  presort_k<<<SS, 256, 0, stream>>>(edge_idx, edge_idx + EE, edge_ptr, row_ptr, ssrc);

  // initial h (fp32, in d_out)
  mgemm0_k<<<SKK / 128, 256, 0, stream>>>(x, Mth, Mtl, h,
                                          nodes, log_probs, root_local, vl, c0v, rev);

  for (int l = 0; l < LLAY; ++l) {
    if (l == 0) {
      gin_mega_k<true><<<SS, 256, 0, stream>>>(h, nullptr, nullptr, nullptr, nullptr,
                                               row_ptr, ssrc, gin_eps, l,
                                               w1th + (size_t)l * HH * HH,
                                               w1tl + (size_t)l * HH * HH,
                                               w2th + (size_t)l * HH * HH,
                                               w2tl + (size_t)l * HH * HH,
                                               b1 + l * HH, b2 + l * HH, zh, zl);
    } else {
      gin_mega_k<false><<<SS, 256, 0, stream>>>(h, uf, bn_stats + (l - 1) * 2 * HH,
                                                gamma + (l - 1) * HH, beta + (l - 1) * HH,
                                                row_ptr, ssrc, gin_eps, l,
                                                w1th + (size_t)l * HH * HH,
                                                w1tl + (size_t)l * HH * HH,
                                                w2th + (size_t)l * HH * HH,
                                                w2tl + (size_t)l * HH * HH,
                                                b1 + l * HH, b2 + l * HH, zh, zl);
    }
    scatter_mean_k<<<NN / 2, 256, 0, stream>>>(zh, zl, node_ptr, rowlist, xah, xal);
    mp2_k<<<SKK / 128, 256, 0, stream>>>(zh, zl, xah, xal,
                                         mp2th + (size_t)l * HH * 256,
                                         mp2tl + (size_t)l * HH * 256,
                                         mp2b + l * HH, uf, nodes,
                                         bn_stats + l * 2 * HH);
  }
  // final BN+residual apply (layer 4) -> h in d_out
  bn_apply_k<<<(SKK * HH / 4) / 256, 256, 0, stream>>>(uf, h, bn_stats + 4 * 2 * HH,
                                                       gamma + 4 * HH, beta + 4 * HH);
}

// Round 7
// 1037.594 us; speedup vs baseline: 1.1721x; 1.0576x over previous
//
#include <hip/hip_runtime.h>
#include <cstdint>

#define NN   50000
#define SS   2048
#define KSUB 64
#define HH   128
#define EE   (SS * 256)
#define SKK  (SS * KSUB)    // 131072
#define LLAY 5
#define NBLK 196            // ceil(NN/256)

typedef __attribute__((ext_vector_type(8))) short bhalf8;
typedef __attribute__((ext_vector_type(4))) float f32x4;

__device__ __forceinline__ ushort f2b(float f) {
  uint u = __builtin_bit_cast(uint, f);
  uint r = (u + 0x7FFFu + ((u >> 16) & 1u)) >> 16;
  return (ushort)r;
}
__device__ __forceinline__ float b2f(ushort u) {
  uint v = ((uint)u) << 16;
  return __builtin_bit_cast(float, v);
}
// split fp32 -> (hi, lo) bf16 pair; hi + lo ~= f with ~2^-18 residual
__device__ __forceinline__ void fsplit(float f, ushort& hi, ushort& lo) {
  hi = f2b(f);
  lo = f2b(f - b2f(hi));
}
// byte offset into a [64][128]-short LDS tile, T2 XOR swizzle (row stride 256B)
__device__ __forceinline__ int zoff(int row, int col) {
  return row * 256 + (((col * 2) & 255) ^ ((row & 7) << 4));
}

// ---------------------------------------------------------------------------
// Fold node_proj through init_proj; emit split bf16 B^T layout [n][c]
// ---------------------------------------------------------------------------
__global__ void fold_M_k(const float* __restrict__ Wn, const float* __restrict__ Wi,
                         ushort* __restrict__ Mth, ushort* __restrict__ Mtl) {
  int c = blockIdx.x, n = threadIdx.x;
  float s = 0.f;
  for (int k = 0; k < HH; ++k) s = fmaf(Wn[c * HH + k], Wi[k * HH + n], s);
  ushort hi, lo; fsplit(s, hi, lo);
  Mth[n * HH + c] = hi; Mtl[n * HH + c] = lo;
}

__global__ void fold_vec_k(const float* __restrict__ Wi, const float* __restrict__ wl,
                           const float* __restrict__ bnb, const float* __restrict__ blb,
                           const float* __restrict__ bi, const float* __restrict__ remb,
                           float* __restrict__ vl, float* __restrict__ c0,
                           float* __restrict__ rev) {
  int n = threadIdx.x;
  float svl = 0.f, sc0 = bi[n], r0 = 0.f, r1 = 0.f;
  for (int k = 0; k < HH; ++k) {
    svl = fmaf(wl[k], Wi[(HH + k) * HH + n], svl);
    sc0 = fmaf(bnb[k], Wi[k * HH + n], sc0);
    sc0 = fmaf(blb[k], Wi[(HH + k) * HH + n], sc0);
    r0  = fmaf(remb[k],      Wi[(2 * HH + k) * HH + n], r0);
    r1  = fmaf(remb[HH + k], Wi[(2 * HH + k) * HH + n], r1);
  }
  vl[n] = svl; c0[n] = sc0; rev[n] = r0; rev[HH + n] = r1;
}

// ---------------------------------------------------------------------------
// Transpose+convert all layer weights to split bf16 B^T layout (one launch).
// ---------------------------------------------------------------------------
__global__ void wconv_k(const float* __restrict__ w1, const float* __restrict__ w2,
                        const float* __restrict__ mp2w,
                        ushort* __restrict__ w1th, ushort* __restrict__ w1tl,
                        ushort* __restrict__ w2th, ushort* __restrict__ w2tl,
                        ushort* __restrict__ mp2th, ushort* __restrict__ mp2tl) {
  int b = blockIdx.x, n = threadIdx.x;
  ushort hi, lo;
  if (b < 640) {
    int l = b >> 7, k = b & 127;
    fsplit(w1[((size_t)l * HH + k) * HH + n], hi, lo);
    w1th[((size_t)l * HH + n) * HH + k] = hi;
    w1tl[((size_t)l * HH + n) * HH + k] = lo;
  } else if (b < 1280) {
    int bb = b - 640; int l = bb >> 7, k = bb & 127;
    fsplit(w2[((size_t)l * HH + k) * HH + n], hi, lo);
    w2th[((size_t)l * HH + n) * HH + k] = hi;
    w2tl[((size_t)l * HH + n) * HH + k] = lo;
  } else {
    int bb = b - 1280; int l = bb >> 8, k = bb & 255;
    fsplit(mp2w[((size_t)l * 256 + k) * HH + n], hi, lo);
    mp2th[((size_t)l * HH + n) * 256 + k] = hi;
    mp2tl[((size_t)l * HH + n) * 256 + k] = lo;
  }
}

// ---------------------------------------------------------------------------
// Node-CSR construction: count -> exclusive scan -> fill
// ---------------------------------------------------------------------------
__global__ void count_k(const int* __restrict__ idc, int* __restrict__ cnt) {
  int i = blockIdx.x * 256 + threadIdx.x;
  if (i < SKK) atomicAdd(&cnt[idc[i]], 1);
}

__global__ void scan1_k(const int* __restrict__ cnt, int* __restrict__ excl,
                        int* __restrict__ bsum) {
  __shared__ int sh[256];
  const int tid = threadIdx.x;
  const int i = blockIdx.x * 256 + tid;
  int v = (i < NN) ? cnt[i] : 0;
  sh[tid] = v;
  __syncthreads();
#pragma unroll
  for (int off = 1; off < 256; off <<= 1) {
    int t = (tid >= off) ? sh[tid - off] : 0;
    __syncthreads();
    sh[tid] += t;
    __syncthreads();
  }
  excl[i] = sh[tid] - v;
  if (tid == 255) bsum[blockIdx.x] = sh[tid];
}

__global__ void scan2_k(int* __restrict__ bsum, int* __restrict__ boff) {
  __shared__ int sh[256];
  const int tid = threadIdx.x;
  int v = (tid < NBLK) ? bsum[tid] : 0;
  sh[tid] = v;
  __syncthreads();
#pragma unroll
  for (int off = 1; off < 256; off <<= 1) {
    int t = (tid >= off) ? sh[tid - off] : 0;
    __syncthreads();
    sh[tid] += t;
    __syncthreads();
  }
  boff[tid] = sh[tid] - v;
}

__global__ void scan3_k(const int* __restrict__ excl, const int* __restrict__ boff,
                        int* __restrict__ node_ptr) {
  int i = blockIdx.x * 256 + threadIdx.x;
  if (i < NN) node_ptr[i] = excl[i] + boff[blockIdx.x];
  if (i == 0) node_ptr[NN] = SKK;
}

__global__ void fill_rows_k(const int* __restrict__ idc, const int* __restrict__ node_ptr,
                            int* __restrict__ cur, int* __restrict__ rowlist) {
  int i = blockIdx.x * 256 + threadIdx.x;
  if (i < SKK) {
    int id = idc[i];
    int pos = atomicAdd(&cur[id], 1);
    rowlist[node_ptr[id] + pos] = i;
  }
}

// ---------------------------------------------------------------------------
// Cross-subgraph scatter-mean as a GATHER. Vectorized: 32 lanes/node,
// 8B uint2 loads per lane (G13 — was scalar 2B ushort loads), 8 nodes/block.
// ---------------------------------------------------------------------------
__launch_bounds__(256)
__global__ void scatter_mean_k(const ushort* __restrict__ zh, const ushort* __restrict__ zl,
                               const int* __restrict__ node_ptr,
                               const int* __restrict__ rowlist,
                               ushort* __restrict__ xah, ushort* __restrict__ xal) {
  const int tid = threadIdx.x;
  const int n = blockIdx.x * 8 + (tid >> 5);
  if (n >= NN) return;
  const int c4 = (tid & 31) * 4;
  const int p0 = node_ptr[n], p1 = node_ptr[n + 1];
  float s0 = 0.f, s1 = 0.f, s2 = 0.f, s3 = 0.f;
  for (int p = p0; p < p1; ++p) {
    const size_t off = (size_t)rowlist[p] * HH + c4;
    uint2 vh = *(const uint2*)(zh + off);
    uint2 vl = *(const uint2*)(zl + off);
    s0 += b2f((ushort)vh.x) + b2f((ushort)vl.x);
    s1 += b2f((ushort)(vh.x >> 16)) + b2f((ushort)(vl.x >> 16));
    s2 += b2f((ushort)vh.y) + b2f((ushort)vl.y);
    s3 += b2f((ushort)(vh.y >> 16)) + b2f((ushort)(vl.y >> 16));
  }
  const float inv = 1.0f / (float)max(p1 - p0, 1);
  ushort h0, l0, h1, l1, h2, l2, h3, l3;
  fsplit(s0 * inv, h0, l0); fsplit(s1 * inv, h1, l1);
  fsplit(s2 * inv, h2, l2); fsplit(s3 * inv, h3, l3);
  uint2 oh, ol;
  oh.x = (uint)h0 | ((uint)h1 << 16); oh.y = (uint)h2 | ((uint)h3 << 16);
  ol.x = (uint)l0 | ((uint)l1 << 16); ol.y = (uint)l2 | ((uint)l3 << 16);
  *(uint2*)(xah + (size_t)n * HH + c4) = oh;
  *(uint2*)(xal + (size_t)n * HH + c4) = ol;
}

// ---------------------------------------------------------------------------
// Per-subgraph counting sort of edges by dst -> CSR
// ---------------------------------------------------------------------------
__launch_bounds__(256)
__global__ void presort_k(const int* __restrict__ e_src, const int* __restrict__ e_dst,
                          const int* __restrict__ edge_ptr, int* __restrict__ row_ptr,
                          int* __restrict__ ssrc) {
  __shared__ int cnt[KSUB];
  __shared__ int base[KSUB];
  __shared__ int cur[KSUB];
  const int s = blockIdx.x, tid = threadIdx.x;
  const int p0 = edge_ptr[s], p1 = edge_ptr[s + 1];
  if (tid < KSUB) cnt[tid] = 0;
  __syncthreads();
  for (int e = p0 + tid; e < p1; e += 256) atomicAdd(&cnt[e_dst[e]], 1);
  __syncthreads();
  if (tid == 0) {
    int a = 0;
    for (int d = 0; d < KSUB; ++d) { base[d] = a; a += cnt[d]; }
  }
  __syncthreads();
  if (tid < KSUB) { row_ptr[s * KSUB + tid] = p0 + base[tid]; cur[tid] = base[tid]; }
  if (s == 0 && tid == 0) row_ptr[SS * KSUB] = edge_ptr[SS];
  __syncthreads();
  for (int e = p0 + tid; e < p1; e += 256) {
    int d = e_dst[e];
    int pos = atomicAdd(&cur[d], 1);
    ssrc[p0 + pos] = e_src[e];
  }
}

// ---------------------------------------------------------------------------
// MEGA kernel: per subgraph (64 rows):
//   phase A: h_new = bn(uf) + h_old (residual) [skip BN if FIRST];
//            BN coef computed INLINE from stats; write h_new, keep fp32 in LDS
//   phase B: GIN aggregation — INTERLEAVED channel mapping (lane q4=(tid&3)*4
//            handles cols q4+16j+k): quad lanes occupy 4 distinct bank windows
//            -> kills the 4-way conflict of the old blocked (q*32) mapping.
//   phase C: split z_agg -> swizzled bf16 LDS tile Z (8B writes, aliases hl)
//   MLP1:    t = relu(Z @ W1 + b1) -> swizzled LDS tile T (aliases Z)
//   MLP2:    z = T @ W2 + b2       -> global zh/zl (split)
// ---------------------------------------------------------------------------
template <bool FIRST>
__launch_bounds__(256, 4)
__global__ void gin_mega_k(float* __restrict__ h, const float* __restrict__ uf,
                           const float* __restrict__ stats,
                           const float* __restrict__ gamma, const float* __restrict__ beta,
                           const int* __restrict__ row_ptr, const int* __restrict__ ssrc,
                           const float* __restrict__ gin_eps, const int layer,
                           const ushort* __restrict__ B1h, const ushort* __restrict__ B1l,
                           const ushort* __restrict__ B2h, const ushort* __restrict__ B2l,
                           const float* __restrict__ bias1, const float* __restrict__ bias2,
                           ushort* __restrict__ zh, ushort* __restrict__ zl) {
  constexpr int LDH = 132;
  __shared__ __align__(16) char smem[KSUB * LDH * 4];   // 33792 B, phase-aliased
  float*  hl = (float*)smem;                 // [64][132] fp32 (phases A,B)
  ushort* Zh = (ushort*)smem;                // [64][128] swizzled (phases C..MLP2)
  ushort* Zl = (ushort*)(smem + KSUB * HH * 2);
  const int s = blockIdx.x, tid = threadIdx.x;
  const size_t base = (size_t)s * KSUB * HH;

  // ---- phase A (BN coef inline; c constant across 'it' since 1024 % 128 == 0) ----
  float csc[4], csh[4];
  const int cb = (tid * 4) & 127;
  if constexpr (!FIRST) {
    const float invM = 1.0f / (float)SKK;
#pragma unroll
    for (int e = 0; e < 4; ++e) {
      const float mu = stats[cb + e] * invM;
      const float var = fmaf(-mu, mu, stats[HH + cb + e] * invM);
      const float sc = rsqrtf(var + 1e-5f) * gamma[cb + e];
      csc[e] = sc; csh[e] = fmaf(-mu, sc, beta[cb + e]);
    }
  }
#pragma unroll
  for (int it = 0; it < 8; ++it) {
    const int idx = it * 1024 + tid * 4;
    const int m = idx >> 7, c = idx & 127;
    float4 hv = *(const float4*)&h[base + idx];
    if constexpr (!FIRST) {
      float4 u4 = *(const float4*)&uf[base + idx];
      hv.x += fmaf(u4.x, csc[0], csh[0]);
      hv.y += fmaf(u4.y, csc[1], csh[1]);
      hv.z += fmaf(u4.z, csc[2], csh[2]);
      hv.w += fmaf(u4.w, csc[3], csh[3]);
      *(float4*)&h[base + idx] = hv;
    }
    *(float4*)&hl[m * LDH + c] = hv;
  }
  __syncthreads();

  // ---- phase B: aggregation (interleaved channel mapping) ----
  const float ep1 = 1.0f + gin_eps[layer];
  const int d = tid >> 2, q4 = (tid & 3) * 4;   // cols q4 + 16*j + k
  const int g = s * KSUB + d;
  const int e0 = row_ptr[g], e1 = row_ptr[g + 1];
  float a[32];
  {
    const float* hp0 = &hl[d * LDH + q4];
#pragma unroll
    for (int j = 0; j < 8; ++j) {
      float4 v = *(const float4*)(hp0 + 16 * j);
      a[4 * j + 0] = ep1 * v.x; a[4 * j + 1] = ep1 * v.y;
      a[4 * j + 2] = ep1 * v.z; a[4 * j + 3] = ep1 * v.w;
    }
    for (int e = e0; e < e1; ++e) {
      const float* hp = &hl[ssrc[e] * LDH + q4];
#pragma unroll
      for (int j = 0; j < 8; ++j) {
        float4 v = *(const float4*)(hp + 16 * j);
        a[4 * j + 0] += v.x; a[4 * j + 1] += v.y;
        a[4 * j + 2] += v.z; a[4 * j + 3] += v.w;
      }
    }
  }
  __syncthreads();          // all hl reads done (Z aliases hl)

  // ---- phase C: split z_agg into swizzled LDS tile (8B writes) ----
#pragma unroll
  for (int j = 0; j < 8; ++j) {
    ushort th[4], tl[4];
#pragma unroll
    for (int k = 0; k < 4; ++k) fsplit(a[4 * j + k], th[k], tl[k]);
    const int o = zoff(d, q4 + 16 * j);
    *(uint2*)((char*)Zh + o) = *(uint2*)th;
    *(uint2*)((char*)Zl + o) = *(uint2*)tl;
  }
  __syncthreads();

  // ---- MLP GEMMs ----
  const int lane = tid & 63, wv = tid >> 6;
  const int fr = lane & 15, quad = lane >> 4;
  const int nj0 = wv * 32 + fr, nj1 = nj0 + 16;

  f32x4 acc[4][2];
#pragma unroll
  for (int i = 0; i < 4; ++i) { acc[i][0] = (f32x4){0,0,0,0}; acc[i][1] = (f32x4){0,0,0,0}; }

  // MLP1: t = relu(Z @ W1 + b1)
#pragma unroll
  for (int ch = 0; ch < 4; ++ch) {
    bhalf8 afh[4], afl[4], bfh[2], bfl[2];
#pragma unroll
    for (int i = 0; i < 4; ++i) {
      const int o = zoff(i * 16 + fr, ch * 32 + quad * 8);
      afh[i] = *(const bhalf8*)((const char*)Zh + o);
      afl[i] = *(const bhalf8*)((const char*)Zl + o);
    }
#pragma unroll
    for (int j = 0; j < 2; ++j) {
      const size_t off = (size_t)(wv * 32 + j * 16 + fr) * HH + ch * 32 + quad * 8;
      bfh[j] = *(const bhalf8*)(B1h + off);
      bfl[j] = *(const bhalf8*)(B1l + off);
    }
#pragma unroll
    for (int i = 0; i < 4; ++i)
#pragma unroll
      for (int j = 0; j < 2; ++j) {
        acc[i][j] = __builtin_amdgcn_mfma_f32_16x16x32_bf16(afh[i], bfh[j], acc[i][j], 0, 0, 0);
        acc[i][j] = __builtin_amdgcn_mfma_f32_16x16x32_bf16(afl[i], bfh[j], acc[i][j], 0, 0, 0);
        acc[i][j] = __builtin_amdgcn_mfma_f32_16x16x32_bf16(afh[i], bfl[j], acc[i][j], 0, 0, 0);
      }
  }
  __syncthreads();          // all Z reads done (T aliases Z)

  // epilogue 1: T = relu(acc + b1), split, into swizzled LDS
  {
    const float b10 = bias1[nj0], b11 = bias1[nj1];
#pragma unroll
    for (int i = 0; i < 4; ++i)
#pragma unroll
      for (int r = 0; r < 4; ++r) {
        const int row = i * 16 + quad * 4 + r;
        const float o0 = fmaxf(acc[i][0][r] + b10, 0.f);
        const float o1 = fmaxf(acc[i][1][r] + b11, 0.f);
        ushort h0, l0, h1, l1; fsplit(o0, h0, l0); fsplit(o1, h1, l1);
        *(ushort*)((char*)Zh + zoff(row, nj0)) = h0;
        *(ushort*)((char*)Zl + zoff(row, nj0)) = l0;
        *(ushort*)((char*)Zh + zoff(row, nj1)) = h1;
        *(ushort*)((char*)Zl + zoff(row, nj1)) = l1;
      }
  }
  __syncthreads();

  // MLP2: z = T @ W2 + b2
#pragma unroll
  for (int i = 0; i < 4; ++i) { acc[i][0] = (f32x4){0,0,0,0}; acc[i][1] = (f32x4){0,0,0,0}; }
#pragma unroll
  for (int ch = 0; ch < 4; ++ch) {
    bhalf8 afh[4], afl[4], bfh[2], bfl[2];
#pragma unroll
    for (int i = 0; i < 4; ++i) {
      const int o = zoff(i * 16 + fr, ch * 32 + quad * 8);
      afh[i] = *(const bhalf8*)((const char*)Zh + o);
      afl[i] = *(const bhalf8*)((const char*)Zl + o);
    }
#pragma unroll
    for (int j = 0; j < 2; ++j) {
      const size_t off = (size_t)(wv * 32 + j * 16 + fr) * HH + ch * 32 + quad * 8;
      bfh[j] = *(const bhalf8*)(B2h + off);
      bfl[j] = *(const bhalf8*)(B2l + off);
    }
#pragma unroll
    for (int i = 0; i < 4; ++i)
#pragma unroll
      for (int j = 0; j < 2; ++j) {
        acc[i][j] = __builtin_amdgcn_mfma_f32_16x16x32_bf16(afh[i], bfh[j], acc[i][j], 0, 0, 0);
        acc[i][j] = __builtin_amdgcn_mfma_f32_16x16x32_bf16(afl[i], bfh[j], acc[i][j], 0, 0, 0);
        acc[i][j] = __builtin_amdgcn_mfma_f32_16x16x32_bf16(afh[i], bfl[j], acc[i][j], 0, 0, 0);
      }
  }

  // epilogue 2: z -> global (split)
  {
    const float b20 = bias2[nj0], b21 = bias2[nj1];
#pragma unroll
    for (int i = 0; i < 4; ++i)
#pragma unroll
      for (int r = 0; r < 4; ++r) {
        const int row = i * 16 + quad * 4 + r;
        const size_t gb = base + (size_t)row * HH;
        const float o0 = acc[i][0][r] + b20;
        const float o1 = acc[i][1][r] + b21;
        ushort h0, l0, h1, l1; fsplit(o0, h0, l0); fsplit(o1, h1, l1);
        zh[gb + nj0] = h0; zl[gb + nj0] = l0;
        zh[gb + nj1] = h1; zl[gb + nj1] = l1;
      }
  }
}

// ---------------------------------------------------------------------------
// MP-2 GEMM: verified 128-row LDS-staged structure + T14 issue-early prefetch.
// ---------------------------------------------------------------------------
__launch_bounds__(256, 3)
__global__ void mp2_k(const ushort* __restrict__ Ah, const ushort* __restrict__ Al,
                      const ushort* __restrict__ A2h, const ushort* __restrict__ A2l,
                      const ushort* __restrict__ Bh, const ushort* __restrict__ Bl,
                      const float* __restrict__ bias, float* __restrict__ Cf,
                      const int* __restrict__ idc, float* __restrict__ stats) {
  constexpr int LDP = 40;   // LDS row stride in shorts
  __shared__ __align__(16) ushort Ash[128 * LDP];
  __shared__ __align__(16) ushort Asl[128 * LDP];
  __shared__ __align__(16) ushort Bsh[128 * LDP];
  __shared__ __align__(16) ushort Bsl[128 * LDP];
  const int tid = threadIdx.x;
  const int row0 = blockIdx.x * 128;
  const int lane = tid & 63, wv = tid >> 6;
  const int wm = (wv >> 1) * 64, wn = (wv & 1) * 64;
  const int fr = lane & 15, quad = lane >> 4;
  const int sr = tid >> 1;            // staging row 0..127
  const int sc = (tid & 1) * 16;      // staging short-offset {0,16}
  const int grow = idc[row0 + sr];    // gather row for K-half 2 (hoisted)

  f32x4 acc[4][4];
#pragma unroll
  for (int i = 0; i < 4; ++i)
#pragma unroll
    for (int j = 0; j < 4; ++j) acc[i][j] = (f32x4){0.f, 0.f, 0.f, 0.f};

  uint4 pa0, pa1, pa2, pa3, pb0, pb1, pb2, pb3;   // prefetch registers
  auto LA = [&](int ch) {
    const ushort *sh_, *sl_;
    if (ch >= 4) {
      const size_t off = (size_t)grow * HH + (ch - 4) * 32 + sc;
      sh_ = A2h + off; sl_ = A2l + off;
    } else {
      const size_t off = (size_t)(row0 + sr) * HH + ch * 32 + sc;
      sh_ = Ah + off; sl_ = Al + off;
    }
    pa0 = *(const uint4*)(sh_);     pa1 = *(const uint4*)(sh_ + 8);
    pa2 = *(const uint4*)(sl_);     pa3 = *(const uint4*)(sl_ + 8);
  };
  auto LB = [&](int ch) {
    const size_t off = (size_t)sr * 256 + ch * 32 + sc;
    pb0 = *(const uint4*)(Bh + off); pb1 = *(const uint4*)(Bh + off + 8);
    pb2 = *(const uint4*)(Bl + off); pb3 = *(const uint4*)(Bl + off + 8);
  };

  LA(0); LB(0);
#pragma unroll
  for (int ch = 0; ch < 8; ++ch) {
    // ---- write prefetched chunk to LDS ----
    *(uint4*)&Ash[sr * LDP + sc]     = pa0;
    *(uint4*)&Ash[sr * LDP + sc + 8] = pa1;
    *(uint4*)&Asl[sr * LDP + sc]     = pa2;
    *(uint4*)&Asl[sr * LDP + sc + 8] = pa3;
    *(uint4*)&Bsh[sr * LDP + sc]     = pb0;
    *(uint4*)&Bsh[sr * LDP + sc + 8] = pb1;
    *(uint4*)&Bsl[sr * LDP + sc]     = pb2;
    *(uint4*)&Bsl[sr * LDP + sc + 8] = pb3;
    __syncthreads();
    // ---- issue next chunk's global loads (fly during MFMA) ----
    if (ch < 7) { LA(ch + 1); LB(ch + 1); }
    // ---- one K=32 MFMA step, bf16x3 ----
    bhalf8 afh[4], afl[4], bfh[4], bfl[4];
#pragma unroll
    for (int i = 0; i < 4; ++i) {
      const int r = (wm + i * 16 + fr) * LDP + quad * 8;
      afh[i] = *(const bhalf8*)&Ash[r];
      afl[i] = *(const bhalf8*)&Asl[r];
    }
#pragma unroll
    for (int j = 0; j < 4; ++j) {
      const int r = (wn + j * 16 + fr) * LDP + quad * 8;
      bfh[j] = *(const bhalf8*)&Bsh[r];
      bfl[j] = *(const bhalf8*)&Bsl[r];
    }
#pragma unroll
    for (int i = 0; i < 4; ++i)
#pragma unroll
      for (int j = 0; j < 4; ++j) {
        acc[i][j] = __builtin_amdgcn_mfma_f32_16x16x32_bf16(afh[i], bfh[j], acc[i][j], 0, 0, 0);
        acc[i][j] = __builtin_amdgcn_mfma_f32_16x16x32_bf16(afl[i], bfh[j], acc[i][j], 0, 0, 0);
        acc[i][j] = __builtin_amdgcn_mfma_f32_16x16x32_bf16(afh[i], bfl[j], acc[i][j], 0, 0, 0);
      }
    __syncthreads();
  }

  // ---- epilogue: relu + bias, uf write, BN stats ----
  const int nj[4] = {wn + fr, wn + 16 + fr, wn + 32 + fr, wn + 48 + fr};
  float bb[4];
#pragma unroll
  for (int j = 0; j < 4; ++j) bb[j] = bias[nj[j]];
  float psum[4] = {0.f, 0.f, 0.f, 0.f}, psq[4] = {0.f, 0.f, 0.f, 0.f};
#pragma unroll
  for (int i = 0; i < 4; ++i)
#pragma unroll
    for (int r = 0; r < 4; ++r) {
      const int m = row0 + wm + i * 16 + quad * 4 + r;
      const size_t base = (size_t)m * HH;
#pragma unroll
      for (int j = 0; j < 4; ++j) {
        float o = fmaxf(acc[i][j][r] + bb[j], 0.f);
        Cf[base + nj[j]] = o;
        psum[j] += o; psq[j] += o * o;
      }
    }
  float* ssum = (float*)Ash;      // dead past last barrier
  float* ssq = ssum + HH;
  if (tid < HH) { ssum[tid] = 0.f; ssq[tid] = 0.f; }
  __syncthreads();
#pragma unroll
  for (int j = 0; j < 4; ++j) {
    atomicAdd(&ssum[nj[j]], psum[j]);
    atomicAdd(&ssq[nj[j]], psq[j]);
  }
  __syncthreads();
  if (tid < HH) {
    unsafeAtomicAdd(&stats[tid], ssum[tid]);
    unsafeAtomicAdd(&stats[HH + tid], ssq[tid]);
  }
}

// ---------------------------------------------------------------------------
// Split-bf16 MFMA GEMM (round-0 verified LDS-staged version) — MODE 0 only.
// ---------------------------------------------------------------------------
__launch_bounds__(256, 2)
__global__ void mgemm0_k(const float* __restrict__ Afp,
                         const ushort* __restrict__ Bh, const ushort* __restrict__ Bl,
                         float* __restrict__ Cf,
                         const int* __restrict__ idc, const float* __restrict__ log_probs,
                         const int* __restrict__ root_local, const float* __restrict__ vl,
                         const float* __restrict__ c0v, const float* __restrict__ rev) {
  constexpr int LDP = 40;
  __shared__ __align__(16) ushort Ash[128 * LDP];
  __shared__ __align__(16) ushort Asl[128 * LDP];
  __shared__ __align__(16) ushort Bsh[128 * LDP];
  __shared__ __align__(16) ushort Bsl[128 * LDP];
  const int tid = threadIdx.x;
  const int row0 = blockIdx.x * 128;
  const int lane = tid & 63, wv = tid >> 6;
  const int wm = (wv >> 1) * 64, wn = (wv & 1) * 64;
  const int fr = lane & 15, quad = lane >> 4;
  const int sr = tid >> 1;
  const int sc = (tid & 1) * 16;

  f32x4 acc[4][4];
#pragma unroll
  for (int i = 0; i < 4; ++i)
#pragma unroll
    for (int j = 0; j < 4; ++j) acc[i][j] = (f32x4){0.f, 0.f, 0.f, 0.f};

  for (int ch = 0; ch < 4; ++ch) {
    {
      const float* src = Afp + (size_t)idc[row0 + sr] * HH + ch * 32 + sc;
      float fv[16];
      *(float4*)&fv[0]  = *(const float4*)(src);
      *(float4*)&fv[4]  = *(const float4*)(src + 4);
      *(float4*)&fv[8]  = *(const float4*)(src + 8);
      *(float4*)&fv[12] = *(const float4*)(src + 12);
      ushort hi[16], lo[16];
#pragma unroll
      for (int e = 0; e < 16; ++e) fsplit(fv[e], hi[e], lo[e]);
      *(uint4*)&Ash[sr * LDP + sc]     = *(uint4*)&hi[0];
      *(uint4*)&Ash[sr * LDP + sc + 8] = *(uint4*)&hi[8];
      *(uint4*)&Asl[sr * LDP + sc]     = *(uint4*)&lo[0];
      *(uint4*)&Asl[sr * LDP + sc + 8] = *(uint4*)&lo[8];
    }
    {
      const size_t off = (size_t)sr * HH + ch * 32 + sc;
      *(uint4*)&Bsh[sr * LDP + sc]     = *(const uint4*)(Bh + off);
      *(uint4*)&Bsh[sr * LDP + sc + 8] = *(const uint4*)(Bh + off + 8);
      *(uint4*)&Bsl[sr * LDP + sc]     = *(const uint4*)(Bl + off);
      *(uint4*)&Bsl[sr * LDP + sc + 8] = *(const uint4*)(Bl + off + 8);
    }
    __syncthreads();
    bhalf8 afh[4], afl[4], bfh[4], bfl[4];
#pragma unroll
    for (int i = 0; i < 4; ++i) {
      const int r = (wm + i * 16 + fr) * LDP + quad * 8;
      afh[i] = *(const bhalf8*)&Ash[r];
      afl[i] = *(const bhalf8*)&Asl[r];
    }
#pragma unroll
    for (int j = 0; j < 4; ++j) {
      const int r = (wn + j * 16 + fr) * LDP + quad * 8;
      bfh[j] = *(const bhalf8*)&Bsh[r];
      bfl[j] = *(const bhalf8*)&Bsl[r];
    }
#pragma unroll
    for (int i = 0; i < 4; ++i)
#pragma unroll
      for (int j = 0; j < 4; ++j) {
        acc[i][j] = __builtin_amdgcn_mfma_f32_16x16x32_bf16(afh[i], bfh[j], acc[i][j], 0, 0, 0);
        acc[i][j] = __builtin_amdgcn_mfma_f32_16x16x32_bf16(afl[i], bfh[j], acc[i][j], 0, 0, 0);
        acc[i][j] = __builtin_amdgcn_mfma_f32_16x16x32_bf16(afh[i], bfl[j], acc[i][j], 0, 0, 0);
      }
    __syncthreads();
  }

  const int nj[4] = {wn + fr, wn + 16 + fr, wn + 32 + fr, wn + 48 + fr};
  float c0a[4], vla[4], re0[4], re1[4];
#pragma unroll
  for (int j = 0; j < 4; ++j) {
    c0a[j] = c0v[nj[j]]; vla[j] = vl[nj[j]];
    re0[j] = rev[nj[j]]; re1[j] = rev[HH + nj[j]];
  }
#pragma unroll
  for (int i = 0; i < 4; ++i)
#pragma unroll
    for (int r = 0; r < 4; ++r) {
      const int m = row0 + wm + i * 16 + quad * 4 + r;
      const int s = m >> 6;
      const float lp = log_probs[s];
      const bool isr = (m & 63) == root_local[s];
      const size_t base = (size_t)m * HH;
#pragma unroll
      for (int j = 0; j < 4; ++j)
        Cf[base + nj[j]] = acc[i][j][r] + c0a[j] + lp * vla[j] + (isr ? re1[j] : re0[j]);
    }
}

// ---------------------------------------------------------------------------
// Final BN apply with residual; coef computed inline from stats.
// ---------------------------------------------------------------------------
__launch_bounds__(256)
__global__ void bn_apply_k(const float* __restrict__ u, float* __restrict__ h,
                           const float* __restrict__ stats,
                           const float* __restrict__ gamma, const float* __restrict__ beta) {
  size_t i4 = (size_t)(blockIdx.x * 256 + threadIdx.x) * 4;
  int c = (int)(i4 & 127);
  const float invM = 1.0f / (float)SKK;
  float sc[4], sh[4];
#pragma unroll
  for (int e = 0; e < 4; ++e) {
    const float mu = stats[c + e] * invM;
    const float var = fmaf(-mu, mu, stats[HH + c + e] * invM);
    const float s = rsqrtf(var + 1e-5f) * gamma[c + e];
    sc[e] = s; sh[e] = fmaf(-mu, s, beta[c + e]);
  }
  float4 uv = *(const float4*)(u + i4);
  float4 hv = *(const float4*)(h + i4);
  float4 o;
  o.x = fmaf(uv.x, sc[0], sh[0]) + hv.x;
  o.y = fmaf(uv.y, sc[1], sh[1]) + hv.y;
  o.z = fmaf(uv.z, sc[2], sh[2]) + hv.z;
  o.w = fmaf(uv.w, sc[3], sh[3]) + hv.w;
  *(float4*)(h + i4) = o;
}

// ---------------------------------------------------------------------------
extern "C" void kernel_launch(void* const* d_in, const int* in_sizes, int n_in,
                              void* d_out, int out_size, void* d_ws, size_t ws_size,
                              hipStream_t stream) {
  const float* x          = (const float*)d_in[0];
  const float* log_probs  = (const float*)d_in[1];
  const float* node_w     = (const float*)d_in[2];
  const float* node_b     = (const float*)d_in[3];
  const float* logp_w     = (const float*)d_in[4];
  const float* logp_b     = (const float*)d_in[5];
  const float* root_emb   = (const float*)d_in[6];
  const float* init_w     = (const float*)d_in[7];
  const float* init_b     = (const float*)d_in[8];
  const float* gin_eps    = (const float*)d_in[9];
  const float* w1         = (const float*)d_in[10];
  const float* b1         = (const float*)d_in[11];
  const float* w2         = (const float*)d_in[12];
  const float* b2         = (const float*)d_in[13];
  const float* mp2w       = (const float*)d_in[14];
  const float* mp2b       = (const float*)d_in[15];
  const float* gamma      = (const float*)d_in[16];
  const float* beta       = (const float*)d_in[17];
  const int*   nodes      = (const int*)d_in[18];
  const int*   root_local = (const int*)d_in[19];
  const int*   edge_idx   = (const int*)d_in[20];
  const int*   edge_ptr   = (const int*)d_in[21];
  float* h = (float*)d_out;   // fp32 residual stream lives in d_out

  // ---- workspace carve ----
  char* wp = (char*)d_ws;
  auto take = [&](size_t bytes) { char* p = wp; wp += (bytes + 255) & ~(size_t)255; return p; };
  ushort* zh    = (ushort*)take((size_t)SKK * HH * 2);   // 32 MB
  ushort* zl    = (ushort*)take((size_t)SKK * HH * 2);
  float*  uf    = (float*)take((size_t)SKK * HH * 4);    // 64 MB
  ushort* xah   = (ushort*)take((size_t)NN * HH * 2);
  ushort* xal   = (ushort*)take((size_t)NN * HH * 2);
  ushort* Mth   = (ushort*)take((size_t)HH * HH * 2);
  ushort* Mtl   = (ushort*)take((size_t)HH * HH * 2);
  ushort* w1th  = (ushort*)take((size_t)LLAY * HH * HH * 2);
  ushort* w1tl  = (ushort*)take((size_t)LLAY * HH * HH * 2);
  ushort* w2th  = (ushort*)take((size_t)LLAY * HH * HH * 2);
  ushort* w2tl  = (ushort*)take((size_t)LLAY * HH * HH * 2);
  ushort* mp2th = (ushort*)take((size_t)LLAY * HH * 256 * 2);
  ushort* mp2tl = (ushort*)take((size_t)LLAY * HH * 256 * 2);
  float* vl       = (float*)take(HH * 4);
  float* c0v      = (float*)take(HH * 4);
  float* rev      = (float*)take(2 * HH * 4);
  float* bn_stats = (float*)take(LLAY * 2 * HH * 4);
  int*   cnti     = (int*)take((size_t)NN * 4);
  int*   excl     = (int*)take((size_t)NBLK * 256 * 4);
  int*   bsum     = (int*)take(256 * 4);
  int*   boff     = (int*)take(256 * 4);
  int*   node_ptr = (int*)take((size_t)(NN + 1) * 4);
  int*   cur      = (int*)take((size_t)NN * 4);
  int*   rowlist  = (int*)take((size_t)SKK * 4);
  int*   row_ptr  = (int*)take((size_t)(SKK + 1) * 4);
  int*   ssrc     = (int*)take((size_t)EE * 4);

  // ---- prologue ----
  hipMemsetAsync(cnti, 0, (size_t)NN * 4, stream);
  hipMemsetAsync(cur, 0, (size_t)NN * 4, stream);
  hipMemsetAsync(bn_stats, 0, LLAY * 2 * HH * 4, stream);
  fold_M_k<<<HH, HH, 0, stream>>>(node_w, init_w, Mth, Mtl);
  fold_vec_k<<<1, HH, 0, stream>>>(init_w, logp_w, node_b, logp_b, init_b, root_emb,
                                   vl, c0v, rev);
  wconv_k<<<2560, HH, 0, stream>>>(w1, w2, mp2w, w1th, w1tl, w2th, w2tl, mp2th, mp2tl);
  count_k<<<SKK / 256, 256, 0, stream>>>(nodes, cnti);
  scan1_k<<<NBLK, 256, 0, stream>>>(cnti, excl, bsum);
  scan2_k<<<1, 256, 0, stream>>>(bsum, boff);
  scan3_k<<<NBLK, 256, 0, stream>>>(excl, boff, node_ptr);
  fill_rows_k<<<SKK / 256, 256, 0, stream>>>(nodes, node_ptr, cur, rowlist);
  presort_k<<<SS, 256, 0, stream>>>(edge_idx, edge_idx + EE, edge_ptr, row_ptr, ssrc);

  // initial h (fp32, in d_out)
  mgemm0_k<<<SKK / 128, 256, 0, stream>>>(x, Mth, Mtl, h,
                                          nodes, log_probs, root_local, vl, c0v, rev);

  for (int l = 0; l < LLAY; ++l) {
    if (l == 0) {
      gin_mega_k<true><<<SS, 256, 0, stream>>>(h, nullptr, nullptr, nullptr, nullptr,
                                               row_ptr, ssrc, gin_eps, l,
                                               w1th + (size_t)l * HH * HH,
                                               w1tl + (size_t)l * HH * HH,
                                               w2th + (size_t)l * HH * HH,
                                               w2tl + (size_t)l * HH * HH,
                                               b1 + l * HH, b2 + l * HH, zh, zl);
    } else {
      gin_mega_k<false><<<SS, 256, 0, stream>>>(h, uf, bn_stats + (l - 1) * 2 * HH,
                                                gamma + (l - 1) * HH, beta + (l - 1) * HH,
                                                row_ptr, ssrc, gin_eps, l,
                                                w1th + (size_t)l * HH * HH,
                                                w1tl + (size_t)l * HH * HH,
                                                w2th + (size_t)l * HH * HH,
                                                w2tl + (size_t)l * HH * HH,
                                                b1 + l * HH, b2 + l * HH, zh, zl);
    }
    scatter_mean_k<<<(NN + 7) / 8, 256, 0, stream>>>(zh, zl, node_ptr, rowlist, xah, xal);
    mp2_k<<<SKK / 128, 256, 0, stream>>>(zh, zl, xah, xal,
                                         mp2th + (size_t)l * HH * 256,
                                         mp2tl + (size_t)l * HH * 256,
                                         mp2b + l * HH, uf, nodes,
                                         bn_stats + l * 2 * HH);
  }
  // final BN+residual apply (layer 4) -> h in d_out
  bn_apply_k<<<(SKK * HH / 4) / 256, 256, 0, stream>>>(uf, h, bn_stats + 4 * 2 * HH,
                                                       gamma + 4 * HH, beta + 4 * HH);
}